// Round 1
// baseline (1212.933 us; speedup 1.0000x reference)
//
#include <hip/hip_runtime.h>
#include <cstddef>

#define N_NODES 50000
#define N_EDGES 625000
#define DIM     128
#define R_REL   200
#define BN_EPS  1e-5f

// ---------------------------------------------------------------------------
// Workspace layout (floats):
//   [S_O: N*D][S_I: N*D][cntO: N][cntI: N][colsum: 128][colsq: 128]   <- zeroed each call
//   [Wcat: 384*128][bias0: 128][bO3: 128][bI3: 128][flag: 1 int]
// ---------------------------------------------------------------------------

// mask dtype detection: in_mask[e] == !out_mask[e] elementwise.
// If stored as 1-byte bools, byte sums are exactly 1 for all e in [0,256).
// If stored as int32 (or f32), bytes 1..3 of each element are 0 -> check fails -> int path.
__global__ void detect_mask_kernel(const unsigned char* __restrict__ in_m,
                                   const unsigned char* __restrict__ out_m,
                                   int* __restrict__ flag) {
    int ok = 1;
    for (int e = 0; e < 256; ++e) ok &= (((int)in_m[e] + (int)out_m[e]) == 1);
    *flag = ok;
}

// Wcat[k][f] = W_sel[f][k] / 3, k in [0,384): 0..127 -> W_S, 128..255 -> W_O, 256..383 -> W_I
__global__ void prep_weights_kernel(const float* __restrict__ WO, const float* __restrict__ WI,
                                    const float* __restrict__ WS, float* __restrict__ Wcat) {
    int k = blockIdx.x;    // 0..383
    int f = threadIdx.x;   // 0..127
    const float third = 1.0f / 3.0f;
    float w;
    if (k < 128)      w = WS[f * DIM + k];
    else if (k < 256) w = WO[f * DIM + (k - 128)];
    else              w = WI[f * DIM + (k - 256)];
    Wcat[k * DIM + f] = w * third;
}

// bias0[f] = (b_S[f] - dot(loop_rel, W_S[f,:])) / 3 ;  bO3/bI3 = b_O/3, b_I/3
__global__ void prep_bias_kernel(const float* __restrict__ WS, const float* __restrict__ bS,
                                 const float* __restrict__ bO, const float* __restrict__ bI,
                                 const float* __restrict__ loop,
                                 float* __restrict__ bias0, float* __restrict__ bO3,
                                 float* __restrict__ bI3) {
    int f = threadIdx.x;  // 128 threads
    float acc = 0.f;
    for (int k = 0; k < DIM; ++k) acc += loop[k] * WS[f * DIM + k];
    const float third = 1.0f / 3.0f;
    bias0[f] = (bS[f] - acc) * third;
    bO3[f]   = bO[f] * third;
    bI3[f]   = bI[f] * third;
}

// r_out[r][f] = dot(r_feats[r,:], W_R[f,:]) + b_R[f]   (only first R rows needed)
__global__ __launch_bounds__(128) void rout_kernel(const float* __restrict__ rf,
                                                   const float* __restrict__ WR,
                                                   const float* __restrict__ bR,
                                                   float* __restrict__ out) {
    int r = blockIdx.x;   // 0..199
    int f = threadIdx.x;  // 0..127
    __shared__ float row[DIM];
    row[f] = rf[r * DIM + f];
    __syncthreads();
    float acc = bR[f];
    for (int k = 0; k < DIM; ++k) acc += row[k] * WR[f * DIM + k];
    out[r * DIM + f] = acc;
}

// Edge scatter: 32 threads per edge (4 floats each).
// v = x[src] - norm * r_feats[etype];  atomicAdd into S_O or S_I at row dst; count per direction.
__global__ __launch_bounds__(256) void edge_kernel(
    const float* __restrict__ x, const float* __restrict__ rf,
    const int* __restrict__ src, const int* __restrict__ dst,
    const int* __restrict__ et, const float* __restrict__ norm,
    const void* __restrict__ omask, const int* __restrict__ flag,
    float* __restrict__ S_O, float* __restrict__ S_I,
    float* __restrict__ cntO, float* __restrict__ cntI) {
    int t = blockIdx.x * 256 + threadIdx.x;
    int e = t >> 5;
    if (e >= N_EDGES) return;
    int lane = t & 31;
    int s = src[e], d = dst[e], r = et[e];
    float nm = norm[e];
    bool m;
    if (*flag) m = (((const unsigned char*)omask)[e] != 0);
    else       m = (((const int*)omask)[e] != 0);

    float4 xv = ((const float4*)x)[s * 32 + lane];
    float4 rv = ((const float4*)rf)[r * 32 + lane];
    float4 v;
    v.x = xv.x - nm * rv.x;
    v.y = xv.y - nm * rv.y;
    v.z = xv.z - nm * rv.z;
    v.w = xv.w - nm * rv.w;

    float* Sp = (m ? S_O : S_I) + (size_t)d * DIM + lane * 4;
    atomicAdd(Sp + 0, v.x);
    atomicAdd(Sp + 1, v.y);
    atomicAdd(Sp + 2, v.z);
    atomicAdd(Sp + 3, v.w);
    if (lane == 0) atomicAdd((m ? cntO : cntI) + d, 1.0f);
}

// Fused GEMM: y[n,:] = [x | S_O | S_I](n,:) @ Wcat + bias0 + cntO[n]*bO3 + cntI[n]*bI3
// (all terms pre-scaled by 1/3). Also accumulates per-column sum / sumsq for BN.
// Block tile: 32 rows x 128 cols, 256 threads, each thread 4 rows x 4 cols.
__global__ __launch_bounds__(256) void gemm_kernel(
    const float* __restrict__ x, const float* __restrict__ S_O, const float* __restrict__ S_I,
    const float* __restrict__ Wcat, const float* __restrict__ bias0,
    const float* __restrict__ bO3, const float* __restrict__ bI3,
    const float* __restrict__ cntO, const float* __restrict__ cntI,
    float* __restrict__ y, float* __restrict__ colsum, float* __restrict__ colsq) {
    __shared__ float As[32][64];
    __shared__ float Ws[64][128];
    __shared__ float redS[8][128];
    __shared__ float redQ[8][128];

    int tid = threadIdx.x;
    int row0 = blockIdx.x * 32;
    int tc = tid & 31;   // col4 index: cols 4*tc .. 4*tc+3
    int tr = tid >> 5;   // 0..7 : rows tr*4 .. tr*4+3 within tile

    float acc[4][4];
#pragma unroll
    for (int i = 0; i < 4; ++i)
#pragma unroll
        for (int j = 0; j < 4; ++j) acc[i][j] = 0.f;

    const float* srcs[3] = {x, S_O, S_I};
    for (int kc = 0; kc < 6; ++kc) {
        const float* Sptr = srcs[kc >> 1];
        int colOff4 = (kc & 1) * 16;  // float4 offset within a 128-float row
        // stage A: 32 rows x 64 cols = 512 float4, 2 per thread
#pragma unroll
        for (int j = 0; j < 2; ++j) {
            int i4 = tid + j * 256;
            int rr = i4 >> 4, c4 = i4 & 15;
            float4 a = make_float4(0.f, 0.f, 0.f, 0.f);
            int grow = row0 + rr;
            if (grow < N_NODES) a = ((const float4*)Sptr)[(size_t)grow * 32 + colOff4 + c4];
            *((float4*)&As[rr][c4 * 4]) = a;
        }
        // stage W: 64 x 128 = 2048 float4, 8 per thread
#pragma unroll
        for (int j = 0; j < 8; ++j) {
            int i4 = tid + j * 256;
            int kk = i4 >> 5, c4 = i4 & 31;
            float4 w = ((const float4*)Wcat)[(size_t)(kc * 64 + kk) * 32 + c4];
            *((float4*)&Ws[kk][c4 * 4]) = w;
        }
        __syncthreads();
#pragma unroll 8
        for (int kk = 0; kk < 64; ++kk) {
            float4 w = *((const float4*)&Ws[kk][tc * 4]);
#pragma unroll
            for (int i = 0; i < 4; ++i) {
                float a = As[tr * 4 + i][kk];
                acc[i][0] += a * w.x;
                acc[i][1] += a * w.y;
                acc[i][2] += a * w.z;
                acc[i][3] += a * w.w;
            }
        }
        __syncthreads();
    }

    // epilogue: biases + store + BN partial sums
    float b0[4], bo[4], bi[4];
#pragma unroll
    for (int j = 0; j < 4; ++j) {
        b0[j] = bias0[tc * 4 + j];
        bo[j] = bO3[tc * 4 + j];
        bi[j] = bI3[tc * 4 + j];
    }
    float ps[4] = {0.f, 0.f, 0.f, 0.f};
    float pq[4] = {0.f, 0.f, 0.f, 0.f};
#pragma unroll
    for (int i = 0; i < 4; ++i) {
        int grow = row0 + tr * 4 + i;
        if (grow < N_NODES) {
            float cO = cntO[grow], cI = cntI[grow];
            float4 v;
            v.x = acc[i][0] + b0[0] + cO * bo[0] + cI * bi[0];
            v.y = acc[i][1] + b0[1] + cO * bo[1] + cI * bi[1];
            v.z = acc[i][2] + b0[2] + cO * bo[2] + cI * bi[2];
            v.w = acc[i][3] + b0[3] + cO * bo[3] + cI * bi[3];
            ((float4*)y)[(size_t)grow * 32 + tc] = v;
            ps[0] += v.x; pq[0] += v.x * v.x;
            ps[1] += v.y; pq[1] += v.y * v.y;
            ps[2] += v.z; pq[2] += v.z * v.z;
            ps[3] += v.w; pq[3] += v.w * v.w;
        }
    }
#pragma unroll
    for (int j = 0; j < 4; ++j) {
        redS[tr][tc * 4 + j] = ps[j];
        redQ[tr][tc * 4 + j] = pq[j];
    }
    __syncthreads();
    if (tid < 128) {
        float s = 0.f, q = 0.f;
#pragma unroll
        for (int t2 = 0; t2 < 8; ++t2) { s += redS[t2][tid]; q += redQ[t2][tid]; }
        atomicAdd(colsum + tid, s);
        atomicAdd(colsq + tid, q);
    }
}

// BN (training-mode batch stats, biased var) + tanh, in place on y.
__global__ __launch_bounds__(256) void bn_apply_kernel(
    float* __restrict__ y, const float* __restrict__ colsum, const float* __restrict__ colsq,
    const float* __restrict__ gamma, const float* __restrict__ beta) {
    __shared__ __align__(16) float sc[DIM];
    __shared__ __align__(16) float sh[DIM];
    int tid = threadIdx.x;
    if (tid < DIM) {
        float mean = colsum[tid] * (1.0f / N_NODES);
        float var  = colsq[tid] * (1.0f / N_NODES) - mean * mean;
        float s = rsqrtf(var + BN_EPS) * gamma[tid];
        sc[tid] = s;
        sh[tid] = beta[tid] - mean * s;
    }
    __syncthreads();
    const int total4 = N_NODES * 32;
    for (int i = blockIdx.x * 256 + tid; i < total4; i += gridDim.x * 256) {
        float4 s4 = ((const float4*)sc)[i & 31];
        float4 h4 = ((const float4*)sh)[i & 31];
        float4 v = ((float4*)y)[i];
        v.x = tanhf(v.x * s4.x + h4.x);
        v.y = tanhf(v.y * s4.y + h4.y);
        v.z = tanhf(v.z * s4.z + h4.z);
        v.w = tanhf(v.w * s4.w + h4.w);
        ((float4*)y)[i] = v;
    }
}

extern "C" void kernel_launch(void* const* d_in, const int* in_sizes, int n_in,
                              void* d_out, int out_size, void* d_ws, size_t ws_size,
                              hipStream_t stream) {
    const float* x        = (const float*)d_in[0];
    const float* r_feats  = (const float*)d_in[1];
    const int*   src      = (const int*)d_in[2];
    const int*   dst      = (const int*)d_in[3];
    const int*   etype    = (const int*)d_in[4];
    const float* norm     = (const float*)d_in[5];
    const void*  in_mask  = d_in[6];
    const void*  out_mask = d_in[7];
    const float* W_O_w    = (const float*)d_in[8];
    const float* W_O_b    = (const float*)d_in[9];
    const float* W_I_w    = (const float*)d_in[10];
    const float* W_I_b    = (const float*)d_in[11];
    const float* W_S_w    = (const float*)d_in[12];
    const float* W_S_b    = (const float*)d_in[13];
    const float* W_R_w    = (const float*)d_in[14];
    const float* W_R_b    = (const float*)d_in[15];
    const float* loop_rel = (const float*)d_in[16];
    const float* bn_gamma = (const float*)d_in[17];
    const float* bn_beta  = (const float*)d_in[18];

    float* ws = (float*)d_ws;
    const size_t ND = (size_t)N_NODES * DIM;
    float* S_O    = ws;
    float* S_I    = S_O + ND;
    float* cntO   = S_I + ND;
    float* cntI   = cntO + N_NODES;
    float* colsum = cntI + N_NODES;
    float* colsq  = colsum + DIM;
    float* Wcat   = colsq + DIM;
    float* bias0  = Wcat + 384 * DIM;
    float* bO3    = bias0 + DIM;
    float* bI3    = bO3 + DIM;
    int*   flag   = (int*)(bI3 + DIM);

    float* y    = (float*)d_out;             // n_out region, N*D floats
    float* rout = (float*)d_out + ND;        // r_out region, R*D floats

    // zero the accumulation region (S_O, S_I, cntO, cntI, colsum, colsq) in one memset
    size_t zero_bytes = (2 * ND + 2 * N_NODES + 2 * DIM) * sizeof(float);
    hipMemsetAsync(S_O, 0, zero_bytes, stream);

    detect_mask_kernel<<<1, 1, 0, stream>>>((const unsigned char*)in_mask,
                                            (const unsigned char*)out_mask, flag);
    prep_weights_kernel<<<384, 128, 0, stream>>>(W_O_w, W_I_w, W_S_w, Wcat);
    prep_bias_kernel<<<1, 128, 0, stream>>>(W_S_w, W_S_b, W_O_b, W_I_b, loop_rel,
                                            bias0, bO3, bI3);
    rout_kernel<<<R_REL, 128, 0, stream>>>(r_feats, W_R_w, W_R_b, rout);

    edge_kernel<<<(N_EDGES * 32) / 256, 256, 0, stream>>>(
        x, r_feats, src, dst, etype, norm, out_mask, flag, S_O, S_I, cntO, cntI);

    gemm_kernel<<<(N_NODES + 31) / 32, 256, 0, stream>>>(
        x, S_O, S_I, Wcat, bias0, bO3, bI3, cntO, cntI, y, colsum, colsq);

    bn_apply_kernel<<<2048, 256, 0, stream>>>(y, colsum, colsq, bn_gamma, bn_beta);
}

// Round 2
// 313.461 us; speedup vs baseline: 3.8695x; 3.8695x over previous
//
#include <hip/hip_runtime.h>
#include <cstddef>

#define N_NODES 50000
#define N_EDGES 625000
#define DIM     128
#define R_REL   200
#define BN_EPS  1e-5f
#define CHUNK   1024
#define NCHUNK  49   // ceil(50000/1024)

// ---------------------------------------------------------------------------
// mask dtype detection: in_mask[e] == !out_mask[e] elementwise.
// If stored as 1-byte bools, byte sums are exactly 1 for all e in [0,256).
__global__ void detect_mask_kernel(const unsigned char* __restrict__ in_m,
                                   const unsigned char* __restrict__ out_m,
                                   int* __restrict__ flag) {
    int ok = 1;
    for (int e = 0; e < 256; ++e) ok &= (((int)in_m[e] + (int)out_m[e]) == 1);
    *flag = ok;
}

// Wcat[k][f] = W_sel[f][k] / 3, k in [0,384): 0..127 -> W_S, 128..255 -> W_O, 256..383 -> W_I
__global__ void prep_weights_kernel(const float* __restrict__ WO, const float* __restrict__ WI,
                                    const float* __restrict__ WS, float* __restrict__ Wcat) {
    int k = blockIdx.x;    // 0..383
    int f = threadIdx.x;   // 0..127
    const float third = 1.0f / 3.0f;
    float w;
    if (k < 128)      w = WS[f * DIM + k];
    else if (k < 256) w = WO[f * DIM + (k - 128)];
    else              w = WI[f * DIM + (k - 256)];
    Wcat[k * DIM + f] = w * third;
}

// bias0[f] = (b_S[f] - dot(loop_rel, W_S[f,:])) / 3 ;  bO3/bI3 = b_O/3, b_I/3
__global__ void prep_bias_kernel(const float* __restrict__ WS, const float* __restrict__ bS,
                                 const float* __restrict__ bO, const float* __restrict__ bI,
                                 const float* __restrict__ loop,
                                 float* __restrict__ bias0, float* __restrict__ bO3,
                                 float* __restrict__ bI3) {
    int f = threadIdx.x;  // 128 threads
    float acc = 0.f;
    for (int k = 0; k < DIM; ++k) acc += loop[k] * WS[f * DIM + k];
    const float third = 1.0f / 3.0f;
    bias0[f] = (bS[f] - acc) * third;
    bO3[f]   = bO[f] * third;
    bI3[f]   = bI[f] * third;
}

// r_out[r][f] = dot(r_feats[r,:], W_R[f,:]) + b_R[f]
__global__ __launch_bounds__(128) void rout_kernel(const float* __restrict__ rf,
                                                   const float* __restrict__ WR,
                                                   const float* __restrict__ bR,
                                                   float* __restrict__ out) {
    int r = blockIdx.x;   // 0..199
    int f = threadIdx.x;  // 0..127
    __shared__ float row[DIM];
    row[f] = rf[r * DIM + f];
    __syncthreads();
    float acc = bR[f];
    for (int k = 0; k < DIM; ++k) acc += row[k] * WR[f * DIM + k];
    out[r * DIM + f] = acc;
}

// ---------------- CSR build: histogram -> scan -> fill ----------------

__global__ __launch_bounds__(256) void hist_kernel(const int* __restrict__ dst,
                                                   int* __restrict__ cnt) {
    int e = blockIdx.x * 256 + threadIdx.x;
    if (e < N_EDGES) atomicAdd(&cnt[dst[e]], 1);
}

// per-chunk totals
__global__ __launch_bounds__(256) void scan1_kernel(const int* __restrict__ cnt,
                                                    int* __restrict__ chunksum) {
    __shared__ int s[256];
    int c = blockIdx.x, t = threadIdx.x;
    int base = c * CHUNK + t * 4;
    int sum = 0;
#pragma unroll
    for (int i = 0; i < 4; ++i) {
        int idx = base + i;
        if (idx < N_NODES) sum += cnt[idx];
    }
    s[t] = sum;
    __syncthreads();
    for (int off = 128; off; off >>= 1) {
        if (t < off) s[t] += s[t + off];
        __syncthreads();
    }
    if (t == 0) chunksum[c] = s[0];
}

// scan chunk totals (tiny), also writes offs[N] = total
__global__ void scan2_kernel(const int* __restrict__ chunksum, int* __restrict__ chunkbase,
                             int* __restrict__ offs) {
    int acc = 0;
    for (int c = 0; c < NCHUNK; ++c) { chunkbase[c] = acc; acc += chunksum[c]; }
    offs[N_NODES] = acc;
}

// exclusive scan within chunk; writes offs[i]; cur aliases cnt (cursor copy)
__global__ __launch_bounds__(256) void scan3_kernel(int* __restrict__ cnt,
                                                    const int* __restrict__ chunkbase,
                                                    int* __restrict__ offs) {
    __shared__ int s[256];
    int c = blockIdx.x, t = threadIdx.x;
    int base = c * CHUNK + t * 4;
    int v[4]; int sum = 0;
#pragma unroll
    for (int i = 0; i < 4; ++i) {
        int idx = base + i;
        v[i] = (idx < N_NODES) ? cnt[idx] : 0;
        sum += v[i];
    }
    s[t] = sum;
    __syncthreads();
    // Hillis-Steele inclusive scan over 256 thread sums
    for (int off = 1; off < 256; off <<= 1) {
        int xv = (t >= off) ? s[t - off] : 0;
        __syncthreads();
        s[t] += xv;
        __syncthreads();
    }
    int run = chunkbase[c] + s[t] - sum;  // exclusive base for this thread
#pragma unroll
    for (int i = 0; i < 4; ++i) {
        int idx = base + i;
        if (idx < N_NODES) {
            offs[idx] = run;
            cnt[idx] = run;  // cursor for fill (reuses cnt storage)
            run += v[i];
        }
    }
}

__global__ __launch_bounds__(256) void fill_kernel(const int* __restrict__ dst,
                                                   int* __restrict__ cur,
                                                   int* __restrict__ eidx) {
    int e = blockIdx.x * 256 + threadIdx.x;
    if (e < N_EDGES) {
        int pos = atomicAdd(&cur[dst[e]], 1);
        eidx[pos] = e;
    }
}

// ---------------- gather-side aggregate: one wave per node ----------------
// S_O[n] = sum over out-edges with dst==n of (x[src]-norm*r[et]); same for S_I.
__global__ __launch_bounds__(256) void aggregate_kernel(
    const float* __restrict__ x, const float* __restrict__ rf,
    const int* __restrict__ src, const int* __restrict__ et,
    const float* __restrict__ norm, const void* __restrict__ omask,
    const int* __restrict__ flag, const int* __restrict__ offs,
    const int* __restrict__ eidx,
    float* __restrict__ S_O, float* __restrict__ S_I,
    float* __restrict__ cntO, float* __restrict__ cntI) {
    int wv = threadIdx.x >> 6;
    int lane = threadIdx.x & 63;
    int n = blockIdx.x * 4 + wv;
    if (n >= N_NODES) return;
    int beg = offs[n], end = offs[n + 1];
    int fl = *flag;
    const unsigned char* mb = (const unsigned char*)omask;
    const int* mi = (const int*)omask;

    float2 aO = make_float2(0.f, 0.f), aI = make_float2(0.f, 0.f);
    int cO = 0, cI = 0;
    for (int j = beg; j < end; ++j) {
        int e = eidx[j];
        int s = src[e], r = et[e];
        float nm = norm[e];
        bool m = fl ? (mb[e] != 0) : (mi[e] != 0);
        float2 xv = ((const float2*)x)[(size_t)s * 64 + lane];
        float2 rv = ((const float2*)rf)[(size_t)r * 64 + lane];
        float2 v = make_float2(xv.x - nm * rv.x, xv.y - nm * rv.y);
        if (m) { aO.x += v.x; aO.y += v.y; ++cO; }
        else   { aI.x += v.x; aI.y += v.y; ++cI; }
    }
    ((float2*)S_O)[(size_t)n * 64 + lane] = aO;
    ((float2*)S_I)[(size_t)n * 64 + lane] = aI;
    if (lane == 0) { cntO[n] = (float)cO; cntI[n] = (float)cI; }
}

// ---------------- fused GEMM + BN stats ----------------
__global__ __launch_bounds__(256) void gemm_kernel(
    const float* __restrict__ x, const float* __restrict__ S_O, const float* __restrict__ S_I,
    const float* __restrict__ Wcat, const float* __restrict__ bias0,
    const float* __restrict__ bO3, const float* __restrict__ bI3,
    const float* __restrict__ cntO, const float* __restrict__ cntI,
    float* __restrict__ y, float* __restrict__ colsum, float* __restrict__ colsq) {
    __shared__ float As[32][64];
    __shared__ float Ws[64][128];
    __shared__ float redS[8][128];
    __shared__ float redQ[8][128];

    int tid = threadIdx.x;
    int row0 = blockIdx.x * 32;
    int tc = tid & 31;
    int tr = tid >> 5;

    float acc[4][4];
#pragma unroll
    for (int i = 0; i < 4; ++i)
#pragma unroll
        for (int j = 0; j < 4; ++j) acc[i][j] = 0.f;

    const float* srcs[3] = {x, S_O, S_I};
    for (int kc = 0; kc < 6; ++kc) {
        const float* Sptr = srcs[kc >> 1];
        int colOff4 = (kc & 1) * 16;
#pragma unroll
        for (int j = 0; j < 2; ++j) {
            int i4 = tid + j * 256;
            int rr = i4 >> 4, c4 = i4 & 15;
            float4 a = make_float4(0.f, 0.f, 0.f, 0.f);
            int grow = row0 + rr;
            if (grow < N_NODES) a = ((const float4*)Sptr)[(size_t)grow * 32 + colOff4 + c4];
            *((float4*)&As[rr][c4 * 4]) = a;
        }
#pragma unroll
        for (int j = 0; j < 8; ++j) {
            int i4 = tid + j * 256;
            int kk = i4 >> 5, c4 = i4 & 31;
            float4 w = ((const float4*)Wcat)[(size_t)(kc * 64 + kk) * 32 + c4];
            *((float4*)&Ws[kk][c4 * 4]) = w;
        }
        __syncthreads();
#pragma unroll 8
        for (int kk = 0; kk < 64; ++kk) {
            float4 w = *((const float4*)&Ws[kk][tc * 4]);
#pragma unroll
            for (int i = 0; i < 4; ++i) {
                float a = As[tr * 4 + i][kk];
                acc[i][0] += a * w.x;
                acc[i][1] += a * w.y;
                acc[i][2] += a * w.z;
                acc[i][3] += a * w.w;
            }
        }
        __syncthreads();
    }

    float b0[4], bo[4], bi[4];
#pragma unroll
    for (int j = 0; j < 4; ++j) {
        b0[j] = bias0[tc * 4 + j];
        bo[j] = bO3[tc * 4 + j];
        bi[j] = bI3[tc * 4 + j];
    }
    float ps[4] = {0.f, 0.f, 0.f, 0.f};
    float pq[4] = {0.f, 0.f, 0.f, 0.f};
#pragma unroll
    for (int i = 0; i < 4; ++i) {
        int grow = row0 + tr * 4 + i;
        if (grow < N_NODES) {
            float cO = cntO[grow], cI = cntI[grow];
            float4 v;
            v.x = acc[i][0] + b0[0] + cO * bo[0] + cI * bi[0];
            v.y = acc[i][1] + b0[1] + cO * bo[1] + cI * bi[1];
            v.z = acc[i][2] + b0[2] + cO * bo[2] + cI * bi[2];
            v.w = acc[i][3] + b0[3] + cO * bo[3] + cI * bi[3];
            ((float4*)y)[(size_t)grow * 32 + tc] = v;
            ps[0] += v.x; pq[0] += v.x * v.x;
            ps[1] += v.y; pq[1] += v.y * v.y;
            ps[2] += v.z; pq[2] += v.z * v.z;
            ps[3] += v.w; pq[3] += v.w * v.w;
        }
    }
#pragma unroll
    for (int j = 0; j < 4; ++j) {
        redS[tr][tc * 4 + j] = ps[j];
        redQ[tr][tc * 4 + j] = pq[j];
    }
    __syncthreads();
    if (tid < 128) {
        float s = 0.f, q = 0.f;
#pragma unroll
        for (int t2 = 0; t2 < 8; ++t2) { s += redS[t2][tid]; q += redQ[t2][tid]; }
        atomicAdd(colsum + tid, s);
        atomicAdd(colsq + tid, q);
    }
}

// BN (training-mode batch stats, biased var) + tanh, in place on y.
__global__ __launch_bounds__(256) void bn_apply_kernel(
    float* __restrict__ y, const float* __restrict__ colsum, const float* __restrict__ colsq,
    const float* __restrict__ gamma, const float* __restrict__ beta) {
    __shared__ __align__(16) float sc[DIM];
    __shared__ __align__(16) float sh[DIM];
    int tid = threadIdx.x;
    if (tid < DIM) {
        float mean = colsum[tid] * (1.0f / N_NODES);
        float var  = colsq[tid] * (1.0f / N_NODES) - mean * mean;
        float s = rsqrtf(var + BN_EPS) * gamma[tid];
        sc[tid] = s;
        sh[tid] = beta[tid] - mean * s;
    }
    __syncthreads();
    const int total4 = N_NODES * 32;
    for (int i = blockIdx.x * 256 + tid; i < total4; i += gridDim.x * 256) {
        float4 s4 = ((const float4*)sc)[i & 31];
        float4 h4 = ((const float4*)sh)[i & 31];
        float4 v = ((float4*)y)[i];
        v.x = tanhf(v.x * s4.x + h4.x);
        v.y = tanhf(v.y * s4.y + h4.y);
        v.z = tanhf(v.z * s4.z + h4.z);
        v.w = tanhf(v.w * s4.w + h4.w);
        ((float4*)y)[i] = v;
    }
}

extern "C" void kernel_launch(void* const* d_in, const int* in_sizes, int n_in,
                              void* d_out, int out_size, void* d_ws, size_t ws_size,
                              hipStream_t stream) {
    const float* x        = (const float*)d_in[0];
    const float* r_feats  = (const float*)d_in[1];
    const int*   src      = (const int*)d_in[2];
    const int*   dst      = (const int*)d_in[3];
    const int*   etype    = (const int*)d_in[4];
    const float* norm     = (const float*)d_in[5];
    const void*  in_mask  = d_in[6];
    const void*  out_mask = d_in[7];
    const float* W_O_w    = (const float*)d_in[8];
    const float* W_O_b    = (const float*)d_in[9];
    const float* W_I_w    = (const float*)d_in[10];
    const float* W_I_b    = (const float*)d_in[11];
    const float* W_S_w    = (const float*)d_in[12];
    const float* W_S_b    = (const float*)d_in[13];
    const float* W_R_w    = (const float*)d_in[14];
    const float* W_R_b    = (const float*)d_in[15];
    const float* loop_rel = (const float*)d_in[16];
    const float* bn_gamma = (const float*)d_in[17];
    const float* bn_beta  = (const float*)d_in[18];

    float* ws = (float*)d_ws;
    const size_t ND = (size_t)N_NODES * DIM;
    float* S_O    = ws;                        // ND
    float* S_I    = S_O + ND;                  // ND
    float* colsum = S_I + ND;                  // 128
    float* colsq  = colsum + DIM;              // 128
    float* Wcat   = colsq + DIM;               // 384*128
    float* bias0  = Wcat + 384 * DIM;          // 128
    float* bO3    = bias0 + DIM;               // 128
    float* bI3    = bO3 + DIM;                 // 128
    float* cntO   = bI3 + DIM;                 // N
    float* cntI   = cntO + N_NODES;            // N
    int*   flag   = (int*)(cntI + N_NODES);    // 4 (padded)
    int*   cnt    = flag + 4;                  // N (doubles as fill cursor)
    int*   offs   = cnt + N_NODES;             // N+1
    int*   chunksum  = offs + N_NODES + 1;     // NCHUNK (pad 64)
    int*   chunkbase = chunksum + 64;          // NCHUNK (pad 64)
    int*   eidx   = chunkbase + 64;            // E

    float* y    = (float*)d_out;               // n_out region, N*D floats
    float* rout = (float*)d_out + ND;          // r_out region, R*D floats

    // zero: histogram counters + BN accumulators (small)
    hipMemsetAsync(cnt, 0, N_NODES * sizeof(int), stream);
    hipMemsetAsync(colsum, 0, 2 * DIM * sizeof(float), stream);

    detect_mask_kernel<<<1, 1, 0, stream>>>((const unsigned char*)in_mask,
                                            (const unsigned char*)out_mask, flag);
    prep_weights_kernel<<<384, 128, 0, stream>>>(W_O_w, W_I_w, W_S_w, Wcat);
    prep_bias_kernel<<<1, 128, 0, stream>>>(W_S_w, W_S_b, W_O_b, W_I_b, loop_rel,
                                            bias0, bO3, bI3);
    rout_kernel<<<R_REL, 128, 0, stream>>>(r_feats, W_R_w, W_R_b, rout);

    // CSR build
    hist_kernel<<<(N_EDGES + 255) / 256, 256, 0, stream>>>(dst, cnt);
    scan1_kernel<<<NCHUNK, 256, 0, stream>>>(cnt, chunksum);
    scan2_kernel<<<1, 1, 0, stream>>>(chunksum, chunkbase, offs);
    scan3_kernel<<<NCHUNK, 256, 0, stream>>>(cnt, chunkbase, offs);
    fill_kernel<<<(N_EDGES + 255) / 256, 256, 0, stream>>>(dst, cnt, eidx);

    // gather-side aggregate (no float atomics, streamed writes)
    aggregate_kernel<<<(N_NODES + 3) / 4, 256, 0, stream>>>(
        x, r_feats, src, etype, norm, out_mask, flag, offs, eidx,
        S_O, S_I, cntO, cntI);

    gemm_kernel<<<(N_NODES + 31) / 32, 256, 0, stream>>>(
        x, S_O, S_I, Wcat, bias0, bO3, bI3, cntO, cntI, y, colsum, colsq);

    bn_apply_kernel<<<2048, 256, 0, stream>>>(y, colsum, colsq, bn_gamma, bn_beta);
}

// Round 3
// 279.541 us; speedup vs baseline: 4.3390x; 1.1213x over previous
//
#include <hip/hip_runtime.h>
#include <cstddef>

#define N_NODES 50000
#define N_EDGES 625000
#define DIM     128
#define R_REL   200
#define BN_EPS  1e-5f
#define CHUNK   1024
#define NCHUNK  49   // ceil(50000/1024)

__device__ __forceinline__ float bfu2f(unsigned int hi16) {
    return __uint_as_float(hi16);
}
__device__ __forceinline__ unsigned int f2bfr(float f) {  // RNE f32->bf16 (as ushort)
    unsigned int u = __float_as_uint(f);
    return (u + 0x7fffu + ((u >> 16) & 1u)) >> 16;
}

// ---------------------------------------------------------------------------
// mask dtype detection: in_mask[e] == !out_mask[e] elementwise.
__global__ void detect_mask_kernel(const unsigned char* __restrict__ in_m,
                                   const unsigned char* __restrict__ out_m,
                                   int* __restrict__ flag) {
    int ok = 1;
    for (int e = 0; e < 256; ++e) ok &= (((int)in_m[e] + (int)out_m[e]) == 1);
    *flag = ok;
}

// f32 -> bf16 (RNE), vectorized x4
__global__ __launch_bounds__(256) void tobf16_kernel(const float* __restrict__ in,
                                                     ushort* __restrict__ out, int n4) {
    int i = blockIdx.x * 256 + threadIdx.x;
    if (i < n4) {
        float4 v = ((const float4*)in)[i];
        ushort4 o;
        o.x = (ushort)f2bfr(v.x);
        o.y = (ushort)f2bfr(v.y);
        o.z = (ushort)f2bfr(v.z);
        o.w = (ushort)f2bfr(v.w);
        ((ushort4*)out)[i] = o;
    }
}

// Wcat[k][f] = W_sel[f][k] / 3, k in [0,384)
__global__ void prep_weights_kernel(const float* __restrict__ WO, const float* __restrict__ WI,
                                    const float* __restrict__ WS, float* __restrict__ Wcat) {
    int k = blockIdx.x;    // 0..383
    int f = threadIdx.x;   // 0..127
    const float third = 1.0f / 3.0f;
    float w;
    if (k < 128)      w = WS[f * DIM + k];
    else if (k < 256) w = WO[f * DIM + (k - 128)];
    else              w = WI[f * DIM + (k - 256)];
    Wcat[k * DIM + f] = w * third;
}

__global__ void prep_bias_kernel(const float* __restrict__ WS, const float* __restrict__ bS,
                                 const float* __restrict__ bO, const float* __restrict__ bI,
                                 const float* __restrict__ loop,
                                 float* __restrict__ bias0, float* __restrict__ bO3,
                                 float* __restrict__ bI3) {
    int f = threadIdx.x;  // 128 threads
    float acc = 0.f;
    for (int k = 0; k < DIM; ++k) acc += loop[k] * WS[f * DIM + k];
    const float third = 1.0f / 3.0f;
    bias0[f] = (bS[f] - acc) * third;
    bO3[f]   = bO[f] * third;
    bI3[f]   = bI[f] * third;
}

__global__ __launch_bounds__(128) void rout_kernel(const float* __restrict__ rf,
                                                   const float* __restrict__ WR,
                                                   const float* __restrict__ bR,
                                                   float* __restrict__ out) {
    int r = blockIdx.x;   // 0..199
    int f = threadIdx.x;  // 0..127
    __shared__ float row[DIM];
    row[f] = rf[r * DIM + f];
    __syncthreads();
    float acc = bR[f];
    for (int k = 0; k < DIM; ++k) acc += row[k] * WR[f * DIM + k];
    out[r * DIM + f] = acc;
}

// ---------------- CSR build: histogram -> scan -> fill packed records -------

__global__ __launch_bounds__(256) void hist_kernel(const int* __restrict__ dst,
                                                   int* __restrict__ cnt) {
    int e = blockIdx.x * 256 + threadIdx.x;
    if (e < N_EDGES) atomicAdd(&cnt[dst[e]], 1);
}

__global__ __launch_bounds__(256) void scan1_kernel(const int* __restrict__ cnt,
                                                    int* __restrict__ chunksum) {
    __shared__ int s[256];
    int c = blockIdx.x, t = threadIdx.x;
    int base = c * CHUNK + t * 4;
    int sum = 0;
#pragma unroll
    for (int i = 0; i < 4; ++i) {
        int idx = base + i;
        if (idx < N_NODES) sum += cnt[idx];
    }
    s[t] = sum;
    __syncthreads();
    for (int off = 128; off; off >>= 1) {
        if (t < off) s[t] += s[t + off];
        __syncthreads();
    }
    if (t == 0) chunksum[c] = s[0];
}

__global__ void scan2_kernel(const int* __restrict__ chunksum, int* __restrict__ chunkbase,
                             int* __restrict__ offs) {
    int acc = 0;
    for (int c = 0; c < NCHUNK; ++c) { chunkbase[c] = acc; acc += chunksum[c]; }
    offs[N_NODES] = acc;
}

__global__ __launch_bounds__(256) void scan3_kernel(int* __restrict__ cnt,
                                                    const int* __restrict__ chunkbase,
                                                    int* __restrict__ offs) {
    __shared__ int s[256];
    int c = blockIdx.x, t = threadIdx.x;
    int base = c * CHUNK + t * 4;
    int v[4]; int sum = 0;
#pragma unroll
    for (int i = 0; i < 4; ++i) {
        int idx = base + i;
        v[i] = (idx < N_NODES) ? cnt[idx] : 0;
        sum += v[i];
    }
    s[t] = sum;
    __syncthreads();
    for (int off = 1; off < 256; off <<= 1) {
        int xv = (t >= off) ? s[t - off] : 0;
        __syncthreads();
        s[t] += xv;
        __syncthreads();
    }
    int run = chunkbase[c] + s[t] - sum;
#pragma unroll
    for (int i = 0; i < 4; ++i) {
        int idx = base + i;
        if (idx < N_NODES) {
            offs[idx] = run;
            cnt[idx] = run;  // cursor for fill
            run += v[i];
        }
    }
}

// fill packed 16B edge records in CSR order: {src, et|mask<<31, norm_bits, 0}
__global__ __launch_bounds__(256) void fill_kernel(
    const int* __restrict__ dst, const int* __restrict__ src,
    const int* __restrict__ et, const float* __restrict__ norm,
    const void* __restrict__ omask, const int* __restrict__ flag,
    int* __restrict__ cur, int4* __restrict__ erec) {
    int e = blockIdx.x * 256 + threadIdx.x;
    if (e >= N_EDGES) return;
    int fl = *flag;
    bool m = fl ? (((const unsigned char*)omask)[e] != 0)
                : (((const int*)omask)[e] != 0);
    int pos = atomicAdd(&cur[dst[e]], 1);
    erec[pos] = make_int4(src[e], et[e] | (m ? 0x80000000 : 0),
                          __float_as_int(norm[e]), 0);
}

// ---------------- gather-side aggregate: one wave per node ----------------
// Reads bf16 x/r, packed edge records; accumulates f32; writes bf16 S rows.
__global__ __launch_bounds__(256) void aggregate_kernel(
    const unsigned int* __restrict__ xb,   // bf16x2 per lane, [N][64]
    const unsigned int* __restrict__ rb,   // [R][64]
    const int4* __restrict__ erec,
    const int* __restrict__ offs,
    unsigned int* __restrict__ S_Ob, unsigned int* __restrict__ S_Ib,
    float* __restrict__ cntO, float* __restrict__ cntI) {
    int wv = threadIdx.x >> 6;
    int lane = threadIdx.x & 63;
    int n = blockIdx.x * 4 + wv;
    if (n >= N_NODES) return;
    int beg = offs[n], end = offs[n + 1];

    float aO0 = 0.f, aO1 = 0.f, aI0 = 0.f, aI1 = 0.f;
    int cO = 0, cI = 0;
    for (int j = beg; j < end; ++j) {
        int4 rec = erec[j];                 // wave-uniform -> broadcast
        int s = rec.x;
        bool m = rec.y < 0;
        int r = rec.y & 0x7fffffff;
        float nm = __int_as_float(rec.z);
        unsigned int xw = xb[(size_t)s * 64 + lane];
        unsigned int rw = rb[(size_t)r * 64 + lane];
        float x0 = bfu2f(xw << 16), x1 = bfu2f(xw & 0xffff0000u);
        float r0 = bfu2f(rw << 16), r1 = bfu2f(rw & 0xffff0000u);
        float v0 = x0 - nm * r0, v1 = x1 - nm * r1;
        if (m) { aO0 += v0; aO1 += v1; ++cO; }
        else   { aI0 += v0; aI1 += v1; ++cI; }
    }
    S_Ob[(size_t)n * 64 + lane] = f2bfr(aO0) | (f2bfr(aO1) << 16);
    S_Ib[(size_t)n * 64 + lane] = f2bfr(aI0) | (f2bfr(aI1) << 16);
    if (lane == 0) { cntO[n] = (float)cO; cntI[n] = (float)cI; }
}

// ---------------- fused GEMM + BN stats ----------------
// A = [x (f32) | S_O (bf16) | S_I (bf16)], W = Wcat (f32, pre-scaled 1/3)
__global__ __launch_bounds__(256) void gemm_kernel(
    const float* __restrict__ x, const ushort* __restrict__ S_Ob,
    const ushort* __restrict__ S_Ib,
    const float* __restrict__ Wcat, const float* __restrict__ bias0,
    const float* __restrict__ bO3, const float* __restrict__ bI3,
    const float* __restrict__ cntO, const float* __restrict__ cntI,
    float* __restrict__ y, float* __restrict__ colsum, float* __restrict__ colsq) {
    __shared__ float As[32][64];
    __shared__ float Ws[64][128];
    __shared__ float redS[8][128];
    __shared__ float redQ[8][128];

    int tid = threadIdx.x;
    int row0 = blockIdx.x * 32;
    int tc = tid & 31;
    int tr = tid >> 5;

    float acc[4][4];
#pragma unroll
    for (int i = 0; i < 4; ++i)
#pragma unroll
        for (int j = 0; j < 4; ++j) acc[i][j] = 0.f;

    for (int kc = 0; kc < 6; ++kc) {
        int colOff4 = (kc & 1) * 16;  // 4-elem group offset within a 128-elem row
        // stage A: 32 rows x 64 cols, 2 chunks of 4 elems per thread
#pragma unroll
        for (int j = 0; j < 2; ++j) {
            int i4 = tid + j * 256;
            int rr = i4 >> 4, c4 = i4 & 15;
            int grow = row0 + rr;
            float4 a = make_float4(0.f, 0.f, 0.f, 0.f);
            if (grow < N_NODES) {
                if (kc < 2) {
                    a = ((const float4*)x)[(size_t)grow * 32 + colOff4 + c4];
                } else {
                    const ushort* Sb = (kc < 4) ? S_Ob : S_Ib;
                    ushort4 u = ((const ushort4*)Sb)[(size_t)grow * 32 + colOff4 + c4];
                    a.x = bfu2f(((unsigned int)u.x) << 16);
                    a.y = bfu2f(((unsigned int)u.y) << 16);
                    a.z = bfu2f(((unsigned int)u.z) << 16);
                    a.w = bfu2f(((unsigned int)u.w) << 16);
                }
            }
            *((float4*)&As[rr][c4 * 4]) = a;
        }
        // stage W: 64 x 128
#pragma unroll
        for (int j = 0; j < 8; ++j) {
            int i4 = tid + j * 256;
            int kk = i4 >> 5, c4 = i4 & 31;
            float4 w = ((const float4*)Wcat)[(size_t)(kc * 64 + kk) * 32 + c4];
            *((float4*)&Ws[kk][c4 * 4]) = w;
        }
        __syncthreads();
#pragma unroll 8
        for (int kk = 0; kk < 64; ++kk) {
            float4 w = *((const float4*)&Ws[kk][tc * 4]);
#pragma unroll
            for (int i = 0; i < 4; ++i) {
                float a = As[tr * 4 + i][kk];
                acc[i][0] += a * w.x;
                acc[i][1] += a * w.y;
                acc[i][2] += a * w.z;
                acc[i][3] += a * w.w;
            }
        }
        __syncthreads();
    }

    float b0[4], bo[4], bi[4];
#pragma unroll
    for (int j = 0; j < 4; ++j) {
        b0[j] = bias0[tc * 4 + j];
        bo[j] = bO3[tc * 4 + j];
        bi[j] = bI3[tc * 4 + j];
    }
    float ps[4] = {0.f, 0.f, 0.f, 0.f};
    float pq[4] = {0.f, 0.f, 0.f, 0.f};
#pragma unroll
    for (int i = 0; i < 4; ++i) {
        int grow = row0 + tr * 4 + i;
        if (grow < N_NODES) {
            float cO = cntO[grow], cI = cntI[grow];
            float4 v;
            v.x = acc[i][0] + b0[0] + cO * bo[0] + cI * bi[0];
            v.y = acc[i][1] + b0[1] + cO * bo[1] + cI * bi[1];
            v.z = acc[i][2] + b0[2] + cO * bo[2] + cI * bi[2];
            v.w = acc[i][3] + b0[3] + cO * bo[3] + cI * bi[3];
            ((float4*)y)[(size_t)grow * 32 + tc] = v;
            ps[0] += v.x; pq[0] += v.x * v.x;
            ps[1] += v.y; pq[1] += v.y * v.y;
            ps[2] += v.z; pq[2] += v.z * v.z;
            ps[3] += v.w; pq[3] += v.w * v.w;
        }
    }
#pragma unroll
    for (int j = 0; j < 4; ++j) {
        redS[tr][tc * 4 + j] = ps[j];
        redQ[tr][tc * 4 + j] = pq[j];
    }
    __syncthreads();
    if (tid < 128) {
        float s = 0.f, q = 0.f;
#pragma unroll
        for (int t2 = 0; t2 < 8; ++t2) { s += redS[t2][tid]; q += redQ[t2][tid]; }
        atomicAdd(colsum + tid, s);
        atomicAdd(colsq + tid, q);
    }
}

// BN + tanh, in place on y.
__global__ __launch_bounds__(256) void bn_apply_kernel(
    float* __restrict__ y, const float* __restrict__ colsum, const float* __restrict__ colsq,
    const float* __restrict__ gamma, const float* __restrict__ beta) {
    __shared__ __align__(16) float sc[DIM];
    __shared__ __align__(16) float sh[DIM];
    int tid = threadIdx.x;
    if (tid < DIM) {
        float mean = colsum[tid] * (1.0f / N_NODES);
        float var  = colsq[tid] * (1.0f / N_NODES) - mean * mean;
        float s = rsqrtf(var + BN_EPS) * gamma[tid];
        sc[tid] = s;
        sh[tid] = beta[tid] - mean * s;
    }
    __syncthreads();
    const int total4 = N_NODES * 32;
    for (int i = blockIdx.x * 256 + tid; i < total4; i += gridDim.x * 256) {
        float4 s4 = ((const float4*)sc)[i & 31];
        float4 h4 = ((const float4*)sh)[i & 31];
        float4 v = ((float4*)y)[i];
        v.x = tanhf(v.x * s4.x + h4.x);
        v.y = tanhf(v.y * s4.y + h4.y);
        v.z = tanhf(v.z * s4.z + h4.z);
        v.w = tanhf(v.w * s4.w + h4.w);
        ((float4*)y)[i] = v;
    }
}

extern "C" void kernel_launch(void* const* d_in, const int* in_sizes, int n_in,
                              void* d_out, int out_size, void* d_ws, size_t ws_size,
                              hipStream_t stream) {
    const float* x        = (const float*)d_in[0];
    const float* r_feats  = (const float*)d_in[1];
    const int*   src      = (const int*)d_in[2];
    const int*   dst      = (const int*)d_in[3];
    const int*   etype    = (const int*)d_in[4];
    const float* norm     = (const float*)d_in[5];
    const void*  in_mask  = d_in[6];
    const void*  out_mask = d_in[7];
    const float* W_O_w    = (const float*)d_in[8];
    const float* W_O_b    = (const float*)d_in[9];
    const float* W_I_w    = (const float*)d_in[10];
    const float* W_I_b    = (const float*)d_in[11];
    const float* W_S_w    = (const float*)d_in[12];
    const float* W_S_b    = (const float*)d_in[13];
    const float* W_R_w    = (const float*)d_in[14];
    const float* W_R_b    = (const float*)d_in[15];
    const float* loop_rel = (const float*)d_in[16];
    const float* bn_gamma = (const float*)d_in[17];
    const float* bn_beta  = (const float*)d_in[18];

    const size_t ND = (size_t)N_NODES * DIM;
    char* p = (char*)d_ws;
    auto alloc = [&](size_t bytes) { void* r = (void*)p; p += (bytes + 255) & ~(size_t)255; return r; };

    ushort* S_Ob = (ushort*)alloc(ND * 2);
    ushort* S_Ib = (ushort*)alloc(ND * 2);
    ushort* xb   = (ushort*)alloc(ND * 2);
    ushort* rb   = (ushort*)alloc((size_t)R_REL * DIM * 2);
    int4*  erec  = (int4*)alloc((size_t)N_EDGES * 16);
    float* Wcat  = (float*)alloc(384 * DIM * 4);
    float* bias0 = (float*)alloc(DIM * 4);
    float* bO3   = (float*)alloc(DIM * 4);
    float* bI3   = (float*)alloc(DIM * 4);
    float* colsum= (float*)alloc(DIM * 4);
    float* colsq = (float*)alloc(DIM * 4);
    float* cntO  = (float*)alloc(N_NODES * 4);
    float* cntI  = (float*)alloc(N_NODES * 4);
    int*   cnt   = (int*)alloc(N_NODES * 4);
    int*   offs  = (int*)alloc((N_NODES + 1) * 4);
    int*   chunksum  = (int*)alloc(NCHUNK * 4);
    int*   chunkbase = (int*)alloc(NCHUNK * 4);
    int*   flag  = (int*)alloc(4);

    float* y    = (float*)d_out;               // n_out region, N*D floats
    float* rout = (float*)d_out + ND;          // r_out region, R*D floats

    hipMemsetAsync(cnt, 0, N_NODES * sizeof(int), stream);
    hipMemsetAsync(colsum, 0, DIM * sizeof(float), stream);
    hipMemsetAsync(colsq, 0, DIM * sizeof(float), stream);

    detect_mask_kernel<<<1, 1, 0, stream>>>((const unsigned char*)in_mask,
                                            (const unsigned char*)out_mask, flag);
    tobf16_kernel<<<(int)((ND / 4 + 255) / 256), 256, 0, stream>>>(x, xb, (int)(ND / 4));
    tobf16_kernel<<<(R_REL * DIM / 4 + 255) / 256, 256, 0, stream>>>(r_feats, rb, R_REL * DIM / 4);
    prep_weights_kernel<<<384, 128, 0, stream>>>(W_O_w, W_I_w, W_S_w, Wcat);
    prep_bias_kernel<<<1, 128, 0, stream>>>(W_S_w, W_S_b, W_O_b, W_I_b, loop_rel,
                                            bias0, bO3, bI3);
    rout_kernel<<<R_REL, 128, 0, stream>>>(r_feats, W_R_w, W_R_b, rout);

    // CSR build
    hist_kernel<<<(N_EDGES + 255) / 256, 256, 0, stream>>>(dst, cnt);
    scan1_kernel<<<NCHUNK, 256, 0, stream>>>(cnt, chunksum);
    scan2_kernel<<<1, 1, 0, stream>>>(chunksum, chunkbase, offs);
    scan3_kernel<<<NCHUNK, 256, 0, stream>>>(cnt, chunkbase, offs);
    fill_kernel<<<(N_EDGES + 255) / 256, 256, 0, stream>>>(
        dst, src, etype, norm, out_mask, flag, cnt, erec);

    aggregate_kernel<<<(N_NODES + 3) / 4, 256, 0, stream>>>(
        (const unsigned int*)xb, (const unsigned int*)rb, erec, offs,
        (unsigned int*)S_Ob, (unsigned int*)S_Ib, cntO, cntI);

    gemm_kernel<<<(N_NODES + 31) / 32, 256, 0, stream>>>(
        x, S_Ob, S_Ib, Wcat, bias0, bO3, bI3, cntO, cntI, y, colsum, colsq);

    bn_apply_kernel<<<2048, 256, 0, stream>>>(y, colsum, colsq, bn_gamma, bn_beta);
}

// Round 5
// 259.781 us; speedup vs baseline: 4.6691x; 1.0761x over previous
//
#include <hip/hip_runtime.h>
#include <cstddef>

#define N_NODES 50000
#define N_EDGES 625000
#define DIM     128
#define R_REL   200
#define BN_EPS  1e-5f
#define CHUNK   1024
#define NCHUNK  49   // ceil(50000/1024)

typedef __bf16 bf16x8 __attribute__((ext_vector_type(8)));
typedef float  f32x4  __attribute__((ext_vector_type(4)));

__device__ __forceinline__ float bfu2f(unsigned int hi16) {
    return __uint_as_float(hi16);
}
__device__ __forceinline__ unsigned int f2bfr(float f) {  // RNE f32->bf16 (as ushort)
    unsigned int u = __float_as_uint(f);
    return (u + 0x7fffu + ((u >> 16) & 1u)) >> 16;
}

// ---------------------------------------------------------------------------
// mask dtype detection: in_mask[e] == !out_mask[e] elementwise.
__global__ void detect_mask_kernel(const unsigned char* __restrict__ in_m,
                                   const unsigned char* __restrict__ out_m,
                                   int* __restrict__ flag) {
    int ok = 1;
    for (int e = 0; e < 256; ++e) ok &= (((int)in_m[e] + (int)out_m[e]) == 1);
    *flag = ok;
}

// f32 -> bf16 (RNE), vectorized x4
__global__ __launch_bounds__(256) void tobf16_kernel(const float* __restrict__ in,
                                                     ushort* __restrict__ out, int n4) {
    int i = blockIdx.x * 256 + threadIdx.x;
    if (i < n4) {
        float4 v = ((const float4*)in)[i];
        ushort4 o;
        o.x = (ushort)f2bfr(v.x);
        o.y = (ushort)f2bfr(v.y);
        o.z = (ushort)f2bfr(v.z);
        o.w = (ushort)f2bfr(v.w);
        ((ushort4*)out)[i] = o;
    }
}

// Wb[f][k] bf16, k in [0,384): [W_S | W_O | W_I](f, k)/3  (row-major [128][384])
__global__ __launch_bounds__(384) void prep_weights_kernel(
    const float* __restrict__ WO, const float* __restrict__ WI,
    const float* __restrict__ WS, ushort* __restrict__ Wb) {
    int f = blockIdx.x;    // 0..127
    int k = threadIdx.x;   // 0..383
    const float third = 1.0f / 3.0f;
    float w;
    if (k < 128)      w = WS[f * DIM + k];
    else if (k < 256) w = WO[f * DIM + (k - 128)];
    else              w = WI[f * DIM + (k - 256)];
    Wb[f * 384 + k] = (ushort)f2bfr(w * third);
}

__global__ void prep_bias_kernel(const float* __restrict__ WS, const float* __restrict__ bS,
                                 const float* __restrict__ bO, const float* __restrict__ bI,
                                 const float* __restrict__ loop,
                                 float* __restrict__ bias0, float* __restrict__ bO3,
                                 float* __restrict__ bI3) {
    int f = threadIdx.x;  // 128 threads
    float acc = 0.f;
    for (int k = 0; k < DIM; ++k) acc += loop[k] * WS[f * DIM + k];
    const float third = 1.0f / 3.0f;
    bias0[f] = (bS[f] - acc) * third;
    bO3[f]   = bO[f] * third;
    bI3[f]   = bI[f] * third;
}

__global__ __launch_bounds__(128) void rout_kernel(const float* __restrict__ rf,
                                                   const float* __restrict__ WR,
                                                   const float* __restrict__ bR,
                                                   float* __restrict__ out) {
    int r = blockIdx.x;   // 0..199
    int f = threadIdx.x;  // 0..127
    __shared__ float row[DIM];
    row[f] = rf[r * DIM + f];
    __syncthreads();
    float acc = bR[f];
    for (int k = 0; k < DIM; ++k) acc += row[k] * WR[f * DIM + k];
    out[r * DIM + f] = acc;
}

// ---------------- CSR build: histogram -> scan -> fill packed records -------

__global__ __launch_bounds__(256) void hist_kernel(const int* __restrict__ dst,
                                                   int* __restrict__ cnt) {
    int e = blockIdx.x * 256 + threadIdx.x;
    if (e < N_EDGES) atomicAdd(&cnt[dst[e]], 1);
}

__global__ __launch_bounds__(256) void scan1_kernel(const int* __restrict__ cnt,
                                                    int* __restrict__ chunksum) {
    __shared__ int s[256];
    int c = blockIdx.x, t = threadIdx.x;
    int base = c * CHUNK + t * 4;
    int sum = 0;
#pragma unroll
    for (int i = 0; i < 4; ++i) {
        int idx = base + i;
        if (idx < N_NODES) sum += cnt[idx];
    }
    s[t] = sum;
    __syncthreads();
    for (int off = 128; off; off >>= 1) {
        if (t < off) s[t] += s[t + off];
        __syncthreads();
    }
    if (t == 0) chunksum[c] = s[0];
}

__global__ void scan2_kernel(const int* __restrict__ chunksum, int* __restrict__ chunkbase,
                             int* __restrict__ offs) {
    int acc = 0;
    for (int c = 0; c < NCHUNK; ++c) { chunkbase[c] = acc; acc += chunksum[c]; }
    offs[N_NODES] = acc;
}

__global__ __launch_bounds__(256) void scan3_kernel(int* __restrict__ cnt,
                                                    const int* __restrict__ chunkbase,
                                                    int* __restrict__ offs) {
    __shared__ int s[256];
    int c = blockIdx.x, t = threadIdx.x;
    int base = c * CHUNK + t * 4;
    int v[4]; int sum = 0;
#pragma unroll
    for (int i = 0; i < 4; ++i) {
        int idx = base + i;
        v[i] = (idx < N_NODES) ? cnt[idx] : 0;
        sum += v[i];
    }
    s[t] = sum;
    __syncthreads();
    for (int off = 1; off < 256; off <<= 1) {
        int xv = (t >= off) ? s[t - off] : 0;
        __syncthreads();
        s[t] += xv;
        __syncthreads();
    }
    int run = chunkbase[c] + s[t] - sum;
#pragma unroll
    for (int i = 0; i < 4; ++i) {
        int idx = base + i;
        if (idx < N_NODES) {
            offs[idx] = run;
            cnt[idx] = run;  // cursor for fill
            run += v[i];
        }
    }
}

// fill packed 16B edge records in CSR order: {src, et|mask<<31, norm_bits, 0}
__global__ __launch_bounds__(256) void fill_kernel(
    const int* __restrict__ dst, const int* __restrict__ src,
    const int* __restrict__ et, const float* __restrict__ norm,
    const void* __restrict__ omask, const int* __restrict__ flag,
    int* __restrict__ cur, int4* __restrict__ erec) {
    int e = blockIdx.x * 256 + threadIdx.x;
    if (e >= N_EDGES) return;
    int fl = *flag;
    bool m = fl ? (((const unsigned char*)omask)[e] != 0)
                : (((const int*)omask)[e] != 0);
    int pos = atomicAdd(&cur[dst[e]], 1);
    erec[pos] = make_int4(src[e], et[e] | (m ? 0x80000000 : 0),
                          __float_as_int(norm[e]), 0);
}

// ---------------- gather-side aggregate: one wave per node ----------------
__global__ __launch_bounds__(256) void aggregate_kernel(
    const unsigned int* __restrict__ xb,   // bf16x2 per lane, [N][64]
    const unsigned int* __restrict__ rb,   // [R][64]
    const int4* __restrict__ erec,
    const int* __restrict__ offs,
    unsigned int* __restrict__ S_Ob, unsigned int* __restrict__ S_Ib,
    float* __restrict__ cntO, float* __restrict__ cntI) {
    int wv = threadIdx.x >> 6;
    int lane = threadIdx.x & 63;
    int n = blockIdx.x * 4 + wv;
    if (n >= N_NODES) return;
    int beg = offs[n], end = offs[n + 1];

    float aO0 = 0.f, aO1 = 0.f, aI0 = 0.f, aI1 = 0.f;
    int cO = 0, cI = 0;
    for (int j = beg; j < end; ++j) {
        int4 rec = erec[j];                 // wave-uniform -> broadcast
        int s = rec.x;
        bool m = rec.y < 0;
        int r = rec.y & 0x7fffffff;
        float nm = __int_as_float(rec.z);
        unsigned int xw = xb[(size_t)s * 64 + lane];
        unsigned int rw = rb[(size_t)r * 64 + lane];
        float x0 = bfu2f(xw << 16), x1 = bfu2f(xw & 0xffff0000u);
        float r0 = bfu2f(rw << 16), r1 = bfu2f(rw & 0xffff0000u);
        float v0 = x0 - nm * r0, v1 = x1 - nm * r1;
        if (m) { aO0 += v0; aO1 += v1; ++cO; }
        else   { aI0 += v0; aI1 += v1; ++cI; }
    }
    S_Ob[(size_t)n * 64 + lane] = f2bfr(aO0) | (f2bfr(aO1) << 16);
    S_Ib[(size_t)n * 64 + lane] = f2bfr(aI0) | (f2bfr(aI1) << 16);
    if (lane == 0) { cntO[n] = (float)cO; cntI[n] = (float)cI; }
}

// ---------------- MFMA GEMM + bias + BN stats ----------------
// y = [xb | S_Ob | S_Ib] (bf16, K=384) @ Wb^T (bf16 [128][384]), f32 accum.
// Block: 4 waves x 16 rows = 64 rows; each wave: 16 rows x 128 cols (8 frags).
__global__ __launch_bounds__(256) void gemm_kernel(
    const ushort* __restrict__ xb, const ushort* __restrict__ S_Ob,
    const ushort* __restrict__ S_Ib, const ushort* __restrict__ Wb,
    const float* __restrict__ bias0, const float* __restrict__ bO3,
    const float* __restrict__ bI3, const float* __restrict__ cntO,
    const float* __restrict__ cntI, float* __restrict__ y,
    float* __restrict__ colsum, float* __restrict__ colsq) {
    __shared__ float redS[4][128];
    __shared__ float redQ[4][128];

    int tid = threadIdx.x;
    int wv = tid >> 6, lane = tid & 63;
    int cl = lane & 15, kg = lane >> 4;
    int wrow0 = blockIdx.x * 64 + wv * 16;

    f32x4 acc[8];
#pragma unroll
    for (int cf = 0; cf < 8; ++cf) acc[cf] = (f32x4){0.f, 0.f, 0.f, 0.f};

    int rowA = wrow0 + cl;
    int rowc = rowA < N_NODES ? rowA : N_NODES - 1;
    const ushort* Abase[3] = {xb, S_Ob, S_Ib};

    for (int kq = 0; kq < 3; ++kq) {
        const ushort* Ap0 = Abase[kq] + (size_t)rowc * 128 + kg * 8;
        const ushort* Bp0 = Wb + (size_t)cl * 384 + kq * 128 + kg * 8;
#pragma unroll
        for (int ks = 0; ks < 4; ++ks) {
            bf16x8 af = __builtin_bit_cast(bf16x8, *(const uint4*)(Ap0 + ks * 32));
#pragma unroll
            for (int cf = 0; cf < 8; ++cf) {
                bf16x8 bv = __builtin_bit_cast(bf16x8,
                    *(const uint4*)(Bp0 + ks * 32 + cf * 16 * 384));
                acc[cf] = __builtin_amdgcn_mfma_f32_16x16x32_bf16(af, bv, acc[cf], 0, 0, 0);
            }
        }
    }

    // epilogue: biases, store, BN partial sums
    float b0a[8], boa[8], bia[8];
#pragma unroll
    for (int cf = 0; cf < 8; ++cf) {
        int col = cf * 16 + cl;
        b0a[cf] = bias0[col]; boa[cf] = bO3[col]; bia[cf] = bI3[col];
    }
    float cOv[4], cIv[4]; int rows[4]; bool rv[4];
#pragma unroll
    for (int r = 0; r < 4; ++r) {
        int row = wrow0 + kg * 4 + r;
        rows[r] = row; rv[r] = row < N_NODES;
        cOv[r] = rv[r] ? cntO[row] : 0.f;
        cIv[r] = rv[r] ? cntI[row] : 0.f;
    }
    float ps[8], pq[8];
#pragma unroll
    for (int cf = 0; cf < 8; ++cf) {
        float s = 0.f, q = 0.f;
        int col = cf * 16 + cl;
#pragma unroll
        for (int r = 0; r < 4; ++r) {
            if (rv[r]) {
                float v = acc[cf][r] + b0a[cf] + cOv[r] * boa[cf] + cIv[r] * bia[cf];
                y[(size_t)rows[r] * DIM + col] = v;
                s += v; q += v * v;
            }
        }
        s += __shfl_xor(s, 16);
        s += __shfl_xor(s, 32);
        q += __shfl_xor(q, 16);
        q += __shfl_xor(q, 32);
        ps[cf] = s; pq[cf] = q;
    }
    if (kg == 0) {
#pragma unroll
        for (int cf = 0; cf < 8; ++cf) {
            redS[wv][cf * 16 + cl] = ps[cf];
            redQ[wv][cf * 16 + cl] = pq[cf];
        }
    }
    __syncthreads();
    if (tid < 128) {
        float s = redS[0][tid] + redS[1][tid] + redS[2][tid] + redS[3][tid];
        float q = redQ[0][tid] + redQ[1][tid] + redQ[2][tid] + redQ[3][tid];
        atomicAdd(colsum + tid, s);
        atomicAdd(colsq + tid, q);
    }
}

// BN + tanh, in place on y.
__global__ __launch_bounds__(256) void bn_apply_kernel(
    float* __restrict__ y, const float* __restrict__ colsum, const float* __restrict__ colsq,
    const float* __restrict__ gamma, const float* __restrict__ beta) {
    __shared__ __align__(16) float sc[DIM];
    __shared__ __align__(16) float sh[DIM];
    int tid = threadIdx.x;
    if (tid < DIM) {
        float mean = colsum[tid] * (1.0f / N_NODES);
        float var  = colsq[tid] * (1.0f / N_NODES) - mean * mean;
        float s = rsqrtf(var + BN_EPS) * gamma[tid];
        sc[tid] = s;
        sh[tid] = beta[tid] - mean * s;
    }
    __syncthreads();
    const int total4 = N_NODES * 32;
    for (int i = blockIdx.x * 256 + tid; i < total4; i += gridDim.x * 256) {
        float4 s4 = ((const float4*)sc)[i & 31];
        float4 h4 = ((const float4*)sh)[i & 31];
        float4 v = ((float4*)y)[i];
        v.x = tanhf(v.x * s4.x + h4.x);
        v.y = tanhf(v.y * s4.y + h4.y);
        v.z = tanhf(v.z * s4.z + h4.z);
        v.w = tanhf(v.w * s4.w + h4.w);
        ((float4*)y)[i] = v;
    }
}

extern "C" void kernel_launch(void* const* d_in, const int* in_sizes, int n_in,
                              void* d_out, int out_size, void* d_ws, size_t ws_size,
                              hipStream_t stream) {
    const float* x        = (const float*)d_in[0];
    const float* r_feats  = (const float*)d_in[1];
    const int*   src      = (const int*)d_in[2];
    const int*   dst      = (const int*)d_in[3];
    const int*   etype    = (const int*)d_in[4];
    const float* norm     = (const float*)d_in[5];
    const void*  in_mask  = d_in[6];
    const void*  out_mask = d_in[7];
    const float* W_O_w    = (const float*)d_in[8];
    const float* W_O_b    = (const float*)d_in[9];
    const float* W_I_w    = (const float*)d_in[10];
    const float* W_I_b    = (const float*)d_in[11];
    const float* W_S_w    = (const float*)d_in[12];
    const float* W_S_b    = (const float*)d_in[13];
    const float* W_R_w    = (const float*)d_in[14];
    const float* W_R_b    = (const float*)d_in[15];
    const float* loop_rel = (const float*)d_in[16];
    const float* bn_gamma = (const float*)d_in[17];
    const float* bn_beta  = (const float*)d_in[18];

    const size_t ND = (size_t)N_NODES * DIM;
    char* p = (char*)d_ws;
    auto alloc = [&](size_t bytes) { void* r = (void*)p; p += (bytes + 255) & ~(size_t)255; return r; };

    ushort* S_Ob = (ushort*)alloc(ND * 2);
    ushort* S_Ib = (ushort*)alloc(ND * 2);
    ushort* xb   = (ushort*)alloc(ND * 2);
    ushort* rb   = (ushort*)alloc((size_t)R_REL * DIM * 2);
    int4*  erec  = (int4*)alloc((size_t)N_EDGES * 16);
    ushort* Wb   = (ushort*)alloc((size_t)DIM * 384 * 2);
    float* bias0 = (float*)alloc(DIM * 4);
    float* bO3   = (float*)alloc(DIM * 4);
    float* bI3   = (float*)alloc(DIM * 4);
    float* colsum= (float*)alloc(DIM * 4);
    float* colsq = (float*)alloc(DIM * 4);
    float* cntO  = (float*)alloc(N_NODES * 4);
    float* cntI  = (float*)alloc(N_NODES * 4);
    int*   cnt   = (int*)alloc(N_NODES * 4);
    int*   offs  = (int*)alloc((N_NODES + 1) * 4);
    int*   chunksum  = (int*)alloc(NCHUNK * 4);
    int*   chunkbase = (int*)alloc(NCHUNK * 4);
    int*   flag  = (int*)alloc(4);

    float* y    = (float*)d_out;               // n_out region, N*D floats
    float* rout = (float*)d_out + ND;          // r_out region, R*D floats

    hipMemsetAsync(cnt, 0, N_NODES * sizeof(int), stream);
    hipMemsetAsync(colsum, 0, DIM * sizeof(float), stream);
    hipMemsetAsync(colsq, 0, DIM * sizeof(float), stream);

    detect_mask_kernel<<<1, 1, 0, stream>>>((const unsigned char*)in_mask,
                                            (const unsigned char*)out_mask, flag);
    tobf16_kernel<<<(int)((ND / 4 + 255) / 256), 256, 0, stream>>>(x, xb, (int)(ND / 4));
    tobf16_kernel<<<(R_REL * DIM / 4 + 255) / 256, 256, 0, stream>>>(r_feats, rb, R_REL * DIM / 4);
    prep_weights_kernel<<<128, 384, 0, stream>>>(W_O_w, W_I_w, W_S_w, Wb);
    prep_bias_kernel<<<1, 128, 0, stream>>>(W_S_w, W_S_b, W_O_b, W_I_b, loop_rel,
                                            bias0, bO3, bI3);
    rout_kernel<<<R_REL, 128, 0, stream>>>(r_feats, W_R_w, W_R_b, rout);

    // CSR build
    hist_kernel<<<(N_EDGES + 255) / 256, 256, 0, stream>>>(dst, cnt);
    scan1_kernel<<<NCHUNK, 256, 0, stream>>>(cnt, chunksum);
    scan2_kernel<<<1, 1, 0, stream>>>(chunksum, chunkbase, offs);
    scan3_kernel<<<NCHUNK, 256, 0, stream>>>(cnt, chunkbase, offs);
    fill_kernel<<<(N_EDGES + 255) / 256, 256, 0, stream>>>(
        dst, src, etype, norm, out_mask, flag, cnt, erec);

    aggregate_kernel<<<(N_NODES + 3) / 4, 256, 0, stream>>>(
        (const unsigned int*)xb, (const unsigned int*)rb, erec, offs,
        (unsigned int*)S_Ob, (unsigned int*)S_Ib, cntO, cntI);

    gemm_kernel<<<(N_NODES + 63) / 64, 256, 0, stream>>>(
        xb, S_Ob, S_Ib, Wb, bias0, bO3, bI3, cntO, cntI, y, colsum, colsq);

    bn_apply_kernel<<<2048, 256, 0, stream>>>(y, colsum, colsq, bn_gamma, bn_beta);
}

// Round 7
// 230.217 us; speedup vs baseline: 5.2686x; 1.1284x over previous
//
#include <hip/hip_runtime.h>
#include <cstddef>

#define N_NODES 50000
#define N_EDGES 625000
#define DIM     128
#define R_REL   200
#define BN_EPS  1e-5f
#define CHUNK   1024
#define NCHUNK  49   // ceil(50000/1024)

typedef __bf16 bf16x8 __attribute__((ext_vector_type(8)));
typedef float  f32x4  __attribute__((ext_vector_type(4)));

__device__ __forceinline__ float bfu2f(unsigned int hi16) {
    return __uint_as_float(hi16);
}
__device__ __forceinline__ unsigned int f2bfr(float f) {  // RNE f32->bf16 (as ushort)
    unsigned int u = __float_as_uint(f);
    return (u + 0x7fffu + ((u >> 16) & 1u)) >> 16;
}

// ---------------------------------------------------------------------------
// mask dtype detection: in_mask[e] == !out_mask[e] elementwise.
__global__ void detect_mask_kernel(const unsigned char* __restrict__ in_m,
                                   const unsigned char* __restrict__ out_m,
                                   int* __restrict__ flag) {
    int ok = 1;
    for (int e = 0; e < 256; ++e) ok &= (((int)in_m[e] + (int)out_m[e]) == 1);
    *flag = ok;
}

// f32 -> bf16 (RNE), vectorized x4
__global__ __launch_bounds__(256) void tobf16_kernel(const float* __restrict__ in,
                                                     ushort* __restrict__ out, int n4) {
    int i = blockIdx.x * 256 + threadIdx.x;
    if (i < n4) {
        float4 v = ((const float4*)in)[i];
        ushort4 o;
        o.x = (ushort)f2bfr(v.x);
        o.y = (ushort)f2bfr(v.y);
        o.z = (ushort)f2bfr(v.z);
        o.w = (ushort)f2bfr(v.w);
        ((ushort4*)out)[i] = o;
    }
}

// Wb[f][k] bf16, k in [0,384): [W_S | W_O | W_I](f, k)/3  (row-major [128][384])
__global__ __launch_bounds__(384) void prep_weights_kernel(
    const float* __restrict__ WO, const float* __restrict__ WI,
    const float* __restrict__ WS, ushort* __restrict__ Wb) {
    int f = blockIdx.x;    // 0..127
    int k = threadIdx.x;   // 0..383
    const float third = 1.0f / 3.0f;
    float w;
    if (k < 128)      w = WS[f * DIM + k];
    else if (k < 256) w = WO[f * DIM + (k - 128)];
    else              w = WI[f * DIM + (k - 256)];
    Wb[f * 384 + k] = (ushort)f2bfr(w * third);
}

__global__ void prep_bias_kernel(const float* __restrict__ WS, const float* __restrict__ bS,
                                 const float* __restrict__ bO, const float* __restrict__ bI,
                                 const float* __restrict__ loop,
                                 float* __restrict__ bias0, float* __restrict__ bO3,
                                 float* __restrict__ bI3) {
    int f = threadIdx.x;  // 128 threads
    float acc = 0.f;
    for (int k = 0; k < DIM; ++k) acc += loop[k] * WS[f * DIM + k];
    const float third = 1.0f / 3.0f;
    bias0[f] = (bS[f] - acc) * third;
    bO3[f]   = bO[f] * third;
    bI3[f]   = bI[f] * third;
}

__global__ __launch_bounds__(128) void rout_kernel(const float* __restrict__ rf,
                                                   const float* __restrict__ WR,
                                                   const float* __restrict__ bR,
                                                   float* __restrict__ out) {
    int r = blockIdx.x;   // 0..199
    int f = threadIdx.x;  // 0..127
    __shared__ float row[DIM];
    row[f] = rf[r * DIM + f];
    __syncthreads();
    float acc = bR[f];
    for (int k = 0; k < DIM; ++k) acc += row[k] * WR[f * DIM + k];
    out[r * DIM + f] = acc;
}

// ---------------- CSR build: histogram -> scan -> fill packed records -------

__global__ __launch_bounds__(256) void hist_kernel(const int* __restrict__ dst,
                                                   int* __restrict__ cnt) {
    int e = blockIdx.x * 256 + threadIdx.x;
    if (e < N_EDGES) atomicAdd(&cnt[dst[e]], 1);
}

__global__ __launch_bounds__(256) void scan1_kernel(const int* __restrict__ cnt,
                                                    int* __restrict__ chunksum) {
    __shared__ int s[256];
    int c = blockIdx.x, t = threadIdx.x;
    int base = c * CHUNK + t * 4;
    int sum = 0;
#pragma unroll
    for (int i = 0; i < 4; ++i) {
        int idx = base + i;
        if (idx < N_NODES) sum += cnt[idx];
    }
    s[t] = sum;
    __syncthreads();
    for (int off = 128; off; off >>= 1) {
        if (t < off) s[t] += s[t + off];
        __syncthreads();
    }
    if (t == 0) chunksum[c] = s[0];
}

__global__ void scan2_kernel(const int* __restrict__ chunksum, int* __restrict__ chunkbase,
                             int* __restrict__ offs) {
    int acc = 0;
    for (int c = 0; c < NCHUNK; ++c) { chunkbase[c] = acc; acc += chunksum[c]; }
    offs[N_NODES] = acc;
}

__global__ __launch_bounds__(256) void scan3_kernel(int* __restrict__ cnt,
                                                    const int* __restrict__ chunkbase,
                                                    int* __restrict__ offs) {
    __shared__ int s[256];
    int c = blockIdx.x, t = threadIdx.x;
    int base = c * CHUNK + t * 4;
    int v[4]; int sum = 0;
#pragma unroll
    for (int i = 0; i < 4; ++i) {
        int idx = base + i;
        v[i] = (idx < N_NODES) ? cnt[idx] : 0;
        sum += v[i];
    }
    s[t] = sum;
    __syncthreads();
    for (int off = 1; off < 256; off <<= 1) {
        int xv = (t >= off) ? s[t - off] : 0;
        __syncthreads();
        s[t] += xv;
        __syncthreads();
    }
    int run = chunkbase[c] + s[t] - sum;
#pragma unroll
    for (int i = 0; i < 4; ++i) {
        int idx = base + i;
        if (idx < N_NODES) {
            offs[idx] = run;
            cnt[idx] = run;  // cursor for fill
            run += v[i];
        }
    }
}

// fill packed 8B edge records in CSR order: {src | et<<16 | mask<<31, norm_bits}
__global__ __launch_bounds__(256) void fill_kernel(
    const int* __restrict__ dst, const int* __restrict__ src,
    const int* __restrict__ et, const float* __restrict__ norm,
    const void* __restrict__ omask, const int* __restrict__ flag,
    int* __restrict__ cur, uint2* __restrict__ erec) {
    int e = blockIdx.x * 256 + threadIdx.x;
    if (e >= N_EDGES) return;
    int fl = *flag;
    bool m = fl ? (((const unsigned char*)omask)[e] != 0)
                : (((const int*)omask)[e] != 0);
    int pos = atomicAdd(&cur[dst[e]], 1);
    unsigned w0 = (unsigned)src[e] | ((unsigned)et[e] << 16) | (m ? 0x80000000u : 0u);
    erec[pos] = make_uint2(w0, (unsigned)__float_as_int(norm[e]));
}

// ---------------- gather-side aggregate: one wave per node ----------------
// 4-way unrolled edge loop, 32-bit offsets, branch-free direction select.
// aT = sum of all contributions; aO = sum over out-edges; aI = aT - aO.
#define AGG_CALC(EX, EY, XW, RW)                                   \
    {                                                              \
        float nm = __uint_as_float(EY);                            \
        float fm = (float)((EX) >> 31);                            \
        float x0 = bfu2f((XW) << 16), x1 = bfu2f((XW) & 0xffff0000u); \
        float r0 = bfu2f((RW) << 16), r1 = bfu2f((RW) & 0xffff0000u); \
        float v0 = __builtin_fmaf(-nm, r0, x0);                    \
        float v1 = __builtin_fmaf(-nm, r1, x1);                    \
        aT0 += v0; aT1 += v1;                                      \
        aO0 = __builtin_fmaf(fm, v0, aO0);                         \
        aO1 = __builtin_fmaf(fm, v1, aO1);                         \
        cOf += fm;                                                 \
    }

__global__ __launch_bounds__(256, 8) void aggregate_kernel(
    const unsigned int* __restrict__ xb,   // bf16x2 per lane, [N][64]
    const unsigned int* __restrict__ rb,   // [R][64]
    const uint2* __restrict__ erec,
    const int* __restrict__ offs,
    unsigned int* __restrict__ S_Ob, unsigned int* __restrict__ S_Ib,
    float* __restrict__ cntO, float* __restrict__ cntI) {
    int wv = threadIdx.x >> 6;
    unsigned lane = threadIdx.x & 63;
    int n = blockIdx.x * 4 + wv;
    if (n >= N_NODES) return;
    int beg = offs[n], end = offs[n + 1];
    int deg = end - beg;

    float aT0 = 0.f, aT1 = 0.f, aO0 = 0.f, aO1 = 0.f, cOf = 0.f;

    int j = beg;
    for (; j + 3 < end; j += 4) {
        uint2 e0 = erec[j], e1 = erec[j + 1], e2 = erec[j + 2], e3 = erec[j + 3];
        unsigned xw0 = xb[((e0.x & 0xffffu) << 6) + lane];
        unsigned rw0 = rb[(((e0.x >> 16) & 0x7fffu) << 6) + lane];
        unsigned xw1 = xb[((e1.x & 0xffffu) << 6) + lane];
        unsigned rw1 = rb[(((e1.x >> 16) & 0x7fffu) << 6) + lane];
        unsigned xw2 = xb[((e2.x & 0xffffu) << 6) + lane];
        unsigned rw2 = rb[(((e2.x >> 16) & 0x7fffu) << 6) + lane];
        unsigned xw3 = xb[((e3.x & 0xffffu) << 6) + lane];
        unsigned rw3 = rb[(((e3.x >> 16) & 0x7fffu) << 6) + lane];
        AGG_CALC(e0.x, e0.y, xw0, rw0)
        AGG_CALC(e1.x, e1.y, xw1, rw1)
        AGG_CALC(e2.x, e2.y, xw2, rw2)
        AGG_CALC(e3.x, e3.y, xw3, rw3)
    }
    for (; j < end; ++j) {
        uint2 e0 = erec[j];
        unsigned xw0 = xb[((e0.x & 0xffffu) << 6) + lane];
        unsigned rw0 = rb[(((e0.x >> 16) & 0x7fffu) << 6) + lane];
        AGG_CALC(e0.x, e0.y, xw0, rw0)
    }

    float aI0 = aT0 - aO0, aI1 = aT1 - aO1;
    S_Ob[((unsigned)n << 6) + lane] = f2bfr(aO0) | (f2bfr(aO1) << 16);
    S_Ib[((unsigned)n << 6) + lane] = f2bfr(aI0) | (f2bfr(aI1) << 16);
    if (lane == 0) { cntO[n] = cOf; cntI[n] = (float)deg - cOf; }
}

// ---------------- MFMA GEMM + bias + BN stats ----------------
// y = [xb | S_Ob | S_Ib] (bf16, K=384) @ Wb^T (bf16 [128][384]), f32 accum.
// Block: 4 waves x 16 rows = 64 rows; each wave: 16 rows x 128 cols (8 frags).
__global__ __launch_bounds__(256) void gemm_kernel(
    const ushort* __restrict__ xb, const ushort* __restrict__ S_Ob,
    const ushort* __restrict__ S_Ib, const ushort* __restrict__ Wb,
    const float* __restrict__ bias0, const float* __restrict__ bO3,
    const float* __restrict__ bI3, const float* __restrict__ cntO,
    const float* __restrict__ cntI, float* __restrict__ y,
    float* __restrict__ colsum, float* __restrict__ colsq) {
    __shared__ float redS[4][128];
    __shared__ float redQ[4][128];

    int tid = threadIdx.x;
    int wv = tid >> 6, lane = tid & 63;
    int cl = lane & 15, kg = lane >> 4;
    int wrow0 = blockIdx.x * 64 + wv * 16;

    f32x4 acc[8];
#pragma unroll
    for (int cf = 0; cf < 8; ++cf) acc[cf] = (f32x4){0.f, 0.f, 0.f, 0.f};

    int rowA = wrow0 + cl;
    int rowc = rowA < N_NODES ? rowA : N_NODES - 1;
    const ushort* Abase[3] = {xb, S_Ob, S_Ib};

    for (int kq = 0; kq < 3; ++kq) {
        const ushort* Ap0 = Abase[kq] + (size_t)rowc * 128 + kg * 8;
        const ushort* Bp0 = Wb + (size_t)cl * 384 + kq * 128 + kg * 8;
#pragma unroll
        for (int ks = 0; ks < 4; ++ks) {
            bf16x8 af = __builtin_bit_cast(bf16x8, *(const uint4*)(Ap0 + ks * 32));
#pragma unroll
            for (int cf = 0; cf < 8; ++cf) {
                bf16x8 bv = __builtin_bit_cast(bf16x8,
                    *(const uint4*)(Bp0 + ks * 32 + cf * 16 * 384));
                acc[cf] = __builtin_amdgcn_mfma_f32_16x16x32_bf16(af, bv, acc[cf], 0, 0, 0);
            }
        }
    }

    // epilogue: biases, store, BN partial sums
    float b0a[8], boa[8], bia[8];
#pragma unroll
    for (int cf = 0; cf < 8; ++cf) {
        int col = cf * 16 + cl;
        b0a[cf] = bias0[col]; boa[cf] = bO3[col]; bia[cf] = bI3[col];
    }
    float cOv[4], cIv[4]; int rows[4]; bool rv[4];
#pragma unroll
    for (int r = 0; r < 4; ++r) {
        int row = wrow0 + kg * 4 + r;
        rows[r] = row; rv[r] = row < N_NODES;
        cOv[r] = rv[r] ? cntO[row] : 0.f;
        cIv[r] = rv[r] ? cntI[row] : 0.f;
    }
    float ps[8], pq[8];
#pragma unroll
    for (int cf = 0; cf < 8; ++cf) {
        float s = 0.f, q = 0.f;
        int col = cf * 16 + cl;
#pragma unroll
        for (int r = 0; r < 4; ++r) {
            if (rv[r]) {
                float v = acc[cf][r] + b0a[cf] + cOv[r] * boa[cf] + cIv[r] * bia[cf];
                y[(size_t)rows[r] * DIM + col] = v;
                s += v; q += v * v;
            }
        }
        s += __shfl_xor(s, 16);
        s += __shfl_xor(s, 32);
        q += __shfl_xor(q, 16);
        q += __shfl_xor(q, 32);
        ps[cf] = s; pq[cf] = q;
    }
    if (kg == 0) {
#pragma unroll
        for (int cf = 0; cf < 8; ++cf) {
            redS[wv][cf * 16 + cl] = ps[cf];
            redQ[wv][cf * 16 + cl] = pq[cf];
        }
    }
    __syncthreads();
    if (tid < 128) {
        float s = redS[0][tid] + redS[1][tid] + redS[2][tid] + redS[3][tid];
        float q = redQ[0][tid] + redQ[1][tid] + redQ[2][tid] + redQ[3][tid];
        atomicAdd(colsum + tid, s);
        atomicAdd(colsq + tid, q);
    }
}

// BN + tanh, in place on y.
__global__ __launch_bounds__(256) void bn_apply_kernel(
    float* __restrict__ y, const float* __restrict__ colsum, const float* __restrict__ colsq,
    const float* __restrict__ gamma, const float* __restrict__ beta) {
    __shared__ __align__(16) float sc[DIM];
    __shared__ __align__(16) float sh[DIM];
    int tid = threadIdx.x;
    if (tid < DIM) {
        float mean = colsum[tid] * (1.0f / N_NODES);
        float var  = colsq[tid] * (1.0f / N_NODES) - mean * mean;
        float s = rsqrtf(var + BN_EPS) * gamma[tid];
        sc[tid] = s;
        sh[tid] = beta[tid] - mean * s;
    }
    __syncthreads();
    const int total4 = N_NODES * 32;
    for (int i = blockIdx.x * 256 + tid; i < total4; i += gridDim.x * 256) {
        float4 s4 = ((const float4*)sc)[i & 31];
        float4 h4 = ((const float4*)sh)[i & 31];
        float4 v = ((float4*)y)[i];
        v.x = tanhf(v.x * s4.x + h4.x);
        v.y = tanhf(v.y * s4.y + h4.y);
        v.z = tanhf(v.z * s4.z + h4.z);
        v.w = tanhf(v.w * s4.w + h4.w);
        ((float4*)y)[i] = v;
    }
}

extern "C" void kernel_launch(void* const* d_in, const int* in_sizes, int n_in,
                              void* d_out, int out_size, void* d_ws, size_t ws_size,
                              hipStream_t stream) {
    const float* x        = (const float*)d_in[0];
    const float* r_feats  = (const float*)d_in[1];
    const int*   src      = (const int*)d_in[2];
    const int*   dst      = (const int*)d_in[3];
    const int*   etype    = (const int*)d_in[4];
    const float* norm     = (const float*)d_in[5];
    const void*  in_mask  = d_in[6];
    const void*  out_mask = d_in[7];
    const float* W_O_w    = (const float*)d_in[8];
    const float* W_O_b    = (const float*)d_in[9];
    const float* W_I_w    = (const float*)d_in[10];
    const float* W_I_b    = (const float*)d_in[11];
    const float* W_S_w    = (const float*)d_in[12];
    const float* W_S_b    = (const float*)d_in[13];
    const float* W_R_w    = (const float*)d_in[14];
    const float* W_R_b    = (const float*)d_in[15];
    const float* loop_rel = (const float*)d_in[16];
    const float* bn_gamma = (const float*)d_in[17];
    const float* bn_beta  = (const float*)d_in[18];

    const size_t ND = (size_t)N_NODES * DIM;
    char* p = (char*)d_ws;
    auto alloc = [&](size_t bytes) { void* r = (void*)p; p += (bytes + 255) & ~(size_t)255; return r; };

    ushort* S_Ob = (ushort*)alloc(ND * 2);
    ushort* S_Ib = (ushort*)alloc(ND * 2);
    ushort* xb   = (ushort*)alloc(ND * 2);
    ushort* rb   = (ushort*)alloc((size_t)R_REL * DIM * 2);
    uint2* erec  = (uint2*)alloc((size_t)N_EDGES * 8);
    ushort* Wb   = (ushort*)alloc((size_t)DIM * 384 * 2);
    float* bias0 = (float*)alloc(DIM * 4);
    float* bO3   = (float*)alloc(DIM * 4);
    float* bI3   = (float*)alloc(DIM * 4);
    float* colsum= (float*)alloc(DIM * 4);
    float* colsq = (float*)alloc(DIM * 4);
    float* cntO  = (float*)alloc(N_NODES * 4);
    float* cntI  = (float*)alloc(N_NODES * 4);
    int*   cnt   = (int*)alloc(N_NODES * 4);
    int*   offs  = (int*)alloc((N_NODES + 1) * 4);
    int*   chunksum  = (int*)alloc(NCHUNK * 4);
    int*   chunkbase = (int*)alloc(NCHUNK * 4);
    int*   flag  = (int*)alloc(4);

    float* y    = (float*)d_out;               // n_out region, N*D floats
    float* rout = (float*)d_out + ND;          // r_out region, R*D floats

    hipMemsetAsync(cnt, 0, N_NODES * sizeof(int), stream);
    hipMemsetAsync(colsum, 0, DIM * sizeof(float), stream);
    hipMemsetAsync(colsq, 0, DIM * sizeof(float), stream);

    detect_mask_kernel<<<1, 1, 0, stream>>>((const unsigned char*)in_mask,
                                            (const unsigned char*)out_mask, flag);
    tobf16_kernel<<<(int)((ND / 4 + 255) / 256), 256, 0, stream>>>(x, xb, (int)(ND / 4));
    tobf16_kernel<<<(R_REL * DIM / 4 + 255) / 256, 256, 0, stream>>>(r_feats, rb, R_REL * DIM / 4);
    prep_weights_kernel<<<128, 384, 0, stream>>>(W_O_w, W_I_w, W_S_w, Wb);
    prep_bias_kernel<<<1, 128, 0, stream>>>(W_S_w, W_S_b, W_O_b, W_I_b, loop_rel,
                                            bias0, bO3, bI3);
    rout_kernel<<<R_REL, 128, 0, stream>>>(r_feats, W_R_w, W_R_b, rout);

    // CSR build
    hist_kernel<<<(N_EDGES + 255) / 256, 256, 0, stream>>>(dst, cnt);
    scan1_kernel<<<NCHUNK, 256, 0, stream>>>(cnt, chunksum);
    scan2_kernel<<<1, 1, 0, stream>>>(chunksum, chunkbase, offs);
    scan3_kernel<<<NCHUNK, 256, 0, stream>>>(cnt, chunkbase, offs);
    fill_kernel<<<(N_EDGES + 255) / 256, 256, 0, stream>>>(
        dst, src, etype, norm, out_mask, flag, cnt, erec);

    aggregate_kernel<<<(N_NODES + 3) / 4, 256, 0, stream>>>(
        (const unsigned int*)xb, (const unsigned int*)rb, erec, offs,
        (unsigned int*)S_Ob, (unsigned int*)S_Ib, cntO, cntI);

    gemm_kernel<<<(N_NODES + 63) / 64, 256, 0, stream>>>(
        xb, S_Ob, S_Ib, Wb, bias0, bO3, bI3, cntO, cntI, y, colsum, colsq);

    bn_apply_kernel<<<2048, 256, 0, stream>>>(y, colsum, colsq, bn_gamma, bn_beta);
}

// Round 10
// 207.363 us; speedup vs baseline: 5.8493x; 1.1102x over previous
//
#include <hip/hip_runtime.h>
#include <cstddef>

#define N_NODES 50000
#define N_EDGES 625000
#define DIM     128
#define R_REL   200
#define BN_EPS  1e-5f
#define CHUNK   1024
#define NCHUNK  49   // ceil(50000/1024)

typedef __bf16 bf16x8 __attribute__((ext_vector_type(8)));
typedef float  f32x4  __attribute__((ext_vector_type(4)));

__device__ __forceinline__ float bfu2f(unsigned int hi16) {
    return __uint_as_float(hi16);
}
__device__ __forceinline__ unsigned int f2bfr(float f) {  // RNE f32->bf16 (as ushort)
    unsigned int u = __float_as_uint(f);
    return (u + 0x7fffu + ((u >> 16) & 1u)) >> 16;
}

// ---------------------------------------------------------------------------
// mask dtype detection: in_mask[e] == !out_mask[e] elementwise.
__global__ void detect_mask_kernel(const unsigned char* __restrict__ in_m,
                                   const unsigned char* __restrict__ out_m,
                                   int* __restrict__ flag) {
    int ok = 1;
    for (int e = 0; e < 256; ++e) ok &= (((int)in_m[e] + (int)out_m[e]) == 1);
    *flag = ok;
}

// f32 -> bf16 (RNE), vectorized x4
__global__ __launch_bounds__(256) void tobf16_kernel(const float* __restrict__ in,
                                                     ushort* __restrict__ out, int n4) {
    int i = blockIdx.x * 256 + threadIdx.x;
    if (i < n4) {
        float4 v = ((const float4*)in)[i];
        ushort4 o;
        o.x = (ushort)f2bfr(v.x);
        o.y = (ushort)f2bfr(v.y);
        o.z = (ushort)f2bfr(v.z);
        o.w = (ushort)f2bfr(v.w);
        ((ushort4*)out)[i] = o;
    }
}

// Wb[f][k] bf16, k in [0,384): [W_S | W_O | W_I](f, k)/3  (row-major [128][384])
__global__ __launch_bounds__(384) void prep_weights_kernel(
    const float* __restrict__ WO, const float* __restrict__ WI,
    const float* __restrict__ WS, ushort* __restrict__ Wb) {
    int f = blockIdx.x;    // 0..127
    int k = threadIdx.x;   // 0..383
    const float third = 1.0f / 3.0f;
    float w;
    if (k < 128)      w = WS[f * DIM + k];
    else if (k < 256) w = WO[f * DIM + (k - 128)];
    else              w = WI[f * DIM + (k - 256)];
    Wb[f * 384 + k] = (ushort)f2bfr(w * third);
}

__global__ void prep_bias_kernel(const float* __restrict__ WS, const float* __restrict__ bS,
                                 const float* __restrict__ bO, const float* __restrict__ bI,
                                 const float* __restrict__ loop,
                                 float* __restrict__ bias0, float* __restrict__ bO3,
                                 float* __restrict__ bI3) {
    int f = threadIdx.x;  // 128 threads
    float acc = 0.f;
    for (int k = 0; k < DIM; ++k) acc += loop[k] * WS[f * DIM + k];
    const float third = 1.0f / 3.0f;
    bias0[f] = (bS[f] - acc) * third;
    bO3[f]   = bO[f] * third;
    bI3[f]   = bI[f] * third;
}

__global__ __launch_bounds__(128) void rout_kernel(const float* __restrict__ rf,
                                                   const float* __restrict__ WR,
                                                   const float* __restrict__ bR,
                                                   float* __restrict__ out) {
    int r = blockIdx.x;   // 0..199
    int f = threadIdx.x;  // 0..127
    __shared__ float row[DIM];
    row[f] = rf[r * DIM + f];
    __syncthreads();
    float acc = bR[f];
    for (int k = 0; k < DIM; ++k) acc += row[k] * WR[f * DIM + k];
    out[r * DIM + f] = acc;
}

// ---------------- CSR build: histogram -> scan -> fill packed records -------

__global__ __launch_bounds__(256) void hist_kernel(const int* __restrict__ dst,
                                                   int* __restrict__ cnt) {
    int e = blockIdx.x * 256 + threadIdx.x;
    if (e < N_EDGES) atomicAdd(&cnt[dst[e]], 1);
}

__global__ __launch_bounds__(256) void scan1_kernel(const int* __restrict__ cnt,
                                                    int* __restrict__ chunksum) {
    __shared__ int s[256];
    int c = blockIdx.x, t = threadIdx.x;
    int base = c * CHUNK + t * 4;
    int sum = 0;
#pragma unroll
    for (int i = 0; i < 4; ++i) {
        int idx = base + i;
        if (idx < N_NODES) sum += cnt[idx];
    }
    s[t] = sum;
    __syncthreads();
    for (int off = 128; off; off >>= 1) {
        if (t < off) s[t] += s[t + off];
        __syncthreads();
    }
    if (t == 0) chunksum[c] = s[0];
}

__global__ void scan2_kernel(const int* __restrict__ chunksum, int* __restrict__ chunkbase,
                             int* __restrict__ offs) {
    int acc = 0;
    for (int c = 0; c < NCHUNK; ++c) { chunkbase[c] = acc; acc += chunksum[c]; }
    offs[N_NODES] = acc;
}

__global__ __launch_bounds__(256) void scan3_kernel(int* __restrict__ cnt,
                                                    const int* __restrict__ chunkbase,
                                                    int* __restrict__ offs) {
    __shared__ int s[256];
    int c = blockIdx.x, t = threadIdx.x;
    int base = c * CHUNK + t * 4;
    int v[4]; int sum = 0;
#pragma unroll
    for (int i = 0; i < 4; ++i) {
        int idx = base + i;
        v[i] = (idx < N_NODES) ? cnt[idx] : 0;
        sum += v[i];
    }
    s[t] = sum;
    __syncthreads();
    for (int off = 1; off < 256; off <<= 1) {
        int xv = (t >= off) ? s[t - off] : 0;
        __syncthreads();
        s[t] += xv;
        __syncthreads();
    }
    int run = chunkbase[c] + s[t] - sum;
#pragma unroll
    for (int i = 0; i < 4; ++i) {
        int idx = base + i;
        if (idx < N_NODES) {
            offs[idx] = run;
            cnt[idx] = run;  // cursor for fill
            run += v[i];
        }
    }
}

// fill packed 8B edge records in CSR order: {src | et<<16 | mask<<31, norm_bits}
__global__ __launch_bounds__(256) void fill_kernel(
    const int* __restrict__ dst, const int* __restrict__ src,
    const int* __restrict__ et, const float* __restrict__ norm,
    const void* __restrict__ omask, const int* __restrict__ flag,
    int* __restrict__ cur, uint2* __restrict__ erec) {
    int e = blockIdx.x * 256 + threadIdx.x;
    if (e >= N_EDGES) return;
    int fl = *flag;
    bool m = fl ? (((const unsigned char*)omask)[e] != 0)
                : (((const int*)omask)[e] != 0);
    int pos = atomicAdd(&cur[dst[e]], 1);
    unsigned w0 = (unsigned)src[e] | ((unsigned)et[e] << 16) | (m ? 0x80000000u : 0u);
    erec[pos] = make_uint2(w0, (unsigned)__float_as_int(norm[e]));
}

// ---------------- gather-side aggregate: one wave per node ----------------
// 4-way unrolled edge loop, 32-bit offsets, branch-free direction select.
// aT = sum of all contributions; aO = sum over out-edges; aI = aT - aO.
#define AGG_CALC(EX, EY, XW, RW)                                   \
    {                                                              \
        float nm = __uint_as_float(EY);                            \
        float fm = (float)((EX) >> 31);                            \
        float x0 = bfu2f((XW) << 16), x1 = bfu2f((XW) & 0xffff0000u); \
        float r0 = bfu2f((RW) << 16), r1 = bfu2f((RW) & 0xffff0000u); \
        float v0 = __builtin_fmaf(-nm, r0, x0);                    \
        float v1 = __builtin_fmaf(-nm, r1, x1);                    \
        aT0 += v0; aT1 += v1;                                      \
        aO0 = __builtin_fmaf(fm, v0, aO0);                         \
        aO1 = __builtin_fmaf(fm, v1, aO1);                         \
        cOf += fm;                                                 \
    }

__global__ __launch_bounds__(256, 8) void aggregate_kernel(
    const unsigned int* __restrict__ xb,   // bf16x2 per lane, [N][64]
    const unsigned int* __restrict__ rb,   // [R][64]
    const uint2* __restrict__ erec,
    const int* __restrict__ offs,
    unsigned int* __restrict__ S_Ob, unsigned int* __restrict__ S_Ib,
    float* __restrict__ cntO, float* __restrict__ cntI) {
    int wv = threadIdx.x >> 6;
    unsigned lane = threadIdx.x & 63;
    int n = blockIdx.x * 4 + wv;
    if (n >= N_NODES) return;
    int beg = offs[n], end = offs[n + 1];
    int deg = end - beg;

    float aT0 = 0.f, aT1 = 0.f, aO0 = 0.f, aO1 = 0.f, cOf = 0.f;

    int j = beg;
    for (; j + 3 < end; j += 4) {
        uint2 e0 = erec[j], e1 = erec[j + 1], e2 = erec[j + 2], e3 = erec[j + 3];
        unsigned xw0 = xb[((e0.x & 0xffffu) << 6) + lane];
        unsigned rw0 = rb[(((e0.x >> 16) & 0x7fffu) << 6) + lane];
        unsigned xw1 = xb[((e1.x & 0xffffu) << 6) + lane];
        unsigned rw1 = rb[(((e1.x >> 16) & 0x7fffu) << 6) + lane];
        unsigned xw2 = xb[((e2.x & 0xffffu) << 6) + lane];
        unsigned rw2 = rb[(((e2.x >> 16) & 0x7fffu) << 6) + lane];
        unsigned xw3 = xb[((e3.x & 0xffffu) << 6) + lane];
        unsigned rw3 = rb[(((e3.x >> 16) & 0x7fffu) << 6) + lane];
        AGG_CALC(e0.x, e0.y, xw0, rw0)
        AGG_CALC(e1.x, e1.y, xw1, rw1)
        AGG_CALC(e2.x, e2.y, xw2, rw2)
        AGG_CALC(e3.x, e3.y, xw3, rw3)
    }
    for (; j < end; ++j) {
        uint2 e0 = erec[j];
        unsigned xw0 = xb[((e0.x & 0xffffu) << 6) + lane];
        unsigned rw0 = rb[(((e0.x >> 16) & 0x7fffu) << 6) + lane];
        AGG_CALC(e0.x, e0.y, xw0, rw0)
    }

    float aI0 = aT0 - aO0, aI1 = aT1 - aO1;
    S_Ob[((unsigned)n << 6) + lane] = f2bfr(aO0) | (f2bfr(aO1) << 16);
    S_Ib[((unsigned)n << 6) + lane] = f2bfr(aI0) | (f2bfr(aI1) << 16);
    if (lane == 0) { cntO[n] = cOf; cntI[n] = (float)deg - cOf; }
}

// ---------------- MFMA GEMM + bias + BN stats ----------------
// y = [xb | S_Ob | S_Ib] (bf16, K=384) @ Wb^T (bf16 [128][384]), f32 accum.
// Block: 4 waves x 32 rows = 128 rows; each wave: 32 rows (2 row-frags) x 128
// cols (8 col-frags). B-frags batched 4-wide so loads overlap; each B-frag is
// reused by 2 MFMAs (the two row groups).  __launch_bounds__(256,4) allows
// ~128 VGPRs: acc 64 + B-batch 16 + A 8 + addressing.
__global__ __launch_bounds__(256, 4) void gemm_kernel(
    const ushort* __restrict__ xb, const ushort* __restrict__ S_Ob,
    const ushort* __restrict__ S_Ib, const ushort* __restrict__ Wb,
    const float* __restrict__ bias0, const float* __restrict__ bO3,
    const float* __restrict__ bI3, const float* __restrict__ cntO,
    const float* __restrict__ cntI, float* __restrict__ y,
    float* __restrict__ colsum, float* __restrict__ colsq) {
    __shared__ float redS[4][128];
    __shared__ float redQ[4][128];

    int tid = threadIdx.x;
    int wv = tid >> 6, lane = tid & 63;
    int cl = lane & 15, kg = lane >> 4;
    int wrow0 = blockIdx.x * 128 + wv * 32;   // wave owns rows [wrow0, wrow0+32)

    f32x4 acc0[8], acc1[8];
#pragma unroll
    for (int cf = 0; cf < 8; ++cf) {
        acc0[cf] = (f32x4){0.f, 0.f, 0.f, 0.f};
        acc1[cf] = (f32x4){0.f, 0.f, 0.f, 0.f};
    }

    int rA0 = wrow0 + cl;       rA0 = rA0 < N_NODES ? rA0 : N_NODES - 1;
    int rA1 = wrow0 + 16 + cl;  rA1 = rA1 < N_NODES ? rA1 : N_NODES - 1;
    const ushort* Abase[3] = {xb, S_Ob, S_Ib};

    for (int kq = 0; kq < 3; ++kq) {
        const ushort* Ap0 = Abase[kq] + (size_t)rA0 * 128 + kg * 8;
        const ushort* Ap1 = Abase[kq] + (size_t)rA1 * 128 + kg * 8;
        const ushort* Bp0 = Wb + (size_t)cl * 384 + kq * 128 + kg * 8;
#pragma unroll
        for (int ks = 0; ks < 4; ++ks) {
            uint4 a0 = *(const uint4*)(Ap0 + ks * 32);
            uint4 a1 = *(const uint4*)(Ap1 + ks * 32);
            uint4 b0[4];
#pragma unroll
            for (int cf = 0; cf < 4; ++cf)
                b0[cf] = *(const uint4*)(Bp0 + ks * 32 + cf * 16 * 384);
            bf16x8 af0 = __builtin_bit_cast(bf16x8, a0);
            bf16x8 af1 = __builtin_bit_cast(bf16x8, a1);
#pragma unroll
            for (int cf = 0; cf < 4; ++cf) {
                bf16x8 bv = __builtin_bit_cast(bf16x8, b0[cf]);
                acc0[cf] = __builtin_amdgcn_mfma_f32_16x16x32_bf16(af0, bv, acc0[cf], 0, 0, 0);
                acc1[cf] = __builtin_amdgcn_mfma_f32_16x16x32_bf16(af1, bv, acc1[cf], 0, 0, 0);
            }
            uint4 b1[4];
#pragma unroll
            for (int cf = 0; cf < 4; ++cf)
                b1[cf] = *(const uint4*)(Bp0 + ks * 32 + (cf + 4) * 16 * 384);
#pragma unroll
            for (int cf = 0; cf < 4; ++cf) {
                bf16x8 bv = __builtin_bit_cast(bf16x8, b1[cf]);
                acc0[cf + 4] = __builtin_amdgcn_mfma_f32_16x16x32_bf16(af0, bv, acc0[cf + 4], 0, 0, 0);
                acc1[cf + 4] = __builtin_amdgcn_mfma_f32_16x16x32_bf16(af1, bv, acc1[cf + 4], 0, 0, 0);
            }
        }
    }

    // epilogue: biases, store, BN partial sums (both row groups)
    float ps[8], pq[8];
#pragma unroll
    for (int cf = 0; cf < 8; ++cf) { ps[cf] = 0.f; pq[cf] = 0.f; }

#pragma unroll
    for (int rg = 0; rg < 2; ++rg) {
        int base = wrow0 + rg * 16 + kg * 4;
        float cOv[4], cIv[4]; bool rv[4];
#pragma unroll
        for (int r = 0; r < 4; ++r) {
            int row = base + r;
            rv[r] = row < N_NODES;
            cOv[r] = rv[r] ? cntO[row] : 0.f;
            cIv[r] = rv[r] ? cntI[row] : 0.f;
        }
#pragma unroll
        for (int cf = 0; cf < 8; ++cf) {
            int col = cf * 16 + cl;
            float b0v = bias0[col], bov = bO3[col], biv = bI3[col];
#pragma unroll
            for (int r = 0; r < 4; ++r) {
                if (rv[r]) {
                    float av = rg == 0 ? acc0[cf][r] : acc1[cf][r];
                    float v = av + b0v + cOv[r] * bov + cIv[r] * biv;
                    y[(size_t)(base + r) * DIM + col] = v;
                    ps[cf] += v; pq[cf] += v * v;
                }
            }
        }
    }
#pragma unroll
    for (int cf = 0; cf < 8; ++cf) {
        float s = ps[cf], q = pq[cf];
        s += __shfl_xor(s, 16);
        s += __shfl_xor(s, 32);
        q += __shfl_xor(q, 16);
        q += __shfl_xor(q, 32);
        ps[cf] = s; pq[cf] = q;
    }
    if (kg == 0) {
#pragma unroll
        for (int cf = 0; cf < 8; ++cf) {
            redS[wv][cf * 16 + cl] = ps[cf];
            redQ[wv][cf * 16 + cl] = pq[cf];
        }
    }
    __syncthreads();
    if (tid < 128) {
        float s = redS[0][tid] + redS[1][tid] + redS[2][tid] + redS[3][tid];
        float q = redQ[0][tid] + redQ[1][tid] + redQ[2][tid] + redQ[3][tid];
        atomicAdd(colsum + tid, s);
        atomicAdd(colsq + tid, q);
    }
}

// BN + tanh, in place on y.
__global__ __launch_bounds__(256) void bn_apply_kernel(
    float* __restrict__ y, const float* __restrict__ colsum, const float* __restrict__ colsq,
    const float* __restrict__ gamma, const float* __restrict__ beta) {
    __shared__ __align__(16) float sc[DIM];
    __shared__ __align__(16) float sh[DIM];
    int tid = threadIdx.x;
    if (tid < DIM) {
        float mean = colsum[tid] * (1.0f / N_NODES);
        float var  = colsq[tid] * (1.0f / N_NODES) - mean * mean;
        float s = rsqrtf(var + BN_EPS) * gamma[tid];
        sc[tid] = s;
        sh[tid] = beta[tid] - mean * s;
    }
    __syncthreads();
    const int total4 = N_NODES * 32;
    for (int i = blockIdx.x * 256 + tid; i < total4; i += gridDim.x * 256) {
        float4 s4 = ((const float4*)sc)[i & 31];
        float4 h4 = ((const float4*)sh)[i & 31];
        float4 v = ((float4*)y)[i];
        v.x = tanhf(v.x * s4.x + h4.x);
        v.y = tanhf(v.y * s4.y + h4.y);
        v.z = tanhf(v.z * s4.z + h4.z);
        v.w = tanhf(v.w * s4.w + h4.w);
        ((float4*)y)[i] = v;
    }
}

extern "C" void kernel_launch(void* const* d_in, const int* in_sizes, int n_in,
                              void* d_out, int out_size, void* d_ws, size_t ws_size,
                              hipStream_t stream) {
    const float* x        = (const float*)d_in[0];
    const float* r_feats  = (const float*)d_in[1];
    const int*   src      = (const int*)d_in[2];
    const int*   dst      = (const int*)d_in[3];
    const int*   etype    = (const int*)d_in[4];
    const float* norm     = (const float*)d_in[5];
    const void*  in_mask  = d_in[6];
    const void*  out_mask = d_in[7];
    const float* W_O_w    = (const float*)d_in[8];
    const float* W_O_b    = (const float*)d_in[9];
    const float* W_I_w    = (const float*)d_in[10];
    const float* W_I_b    = (const float*)d_in[11];
    const float* W_S_w    = (const float*)d_in[12];
    const float* W_S_b    = (const float*)d_in[13];
    const float* W_R_w    = (const float*)d_in[14];
    const float* W_R_b    = (const float*)d_in[15];
    const float* loop_rel = (const float*)d_in[16];
    const float* bn_gamma = (const float*)d_in[17];
    const float* bn_beta  = (const float*)d_in[18];

    const size_t ND = (size_t)N_NODES * DIM;
    char* p = (char*)d_ws;
    auto alloc = [&](size_t bytes) { void* r = (void*)p; p += (bytes + 255) & ~(size_t)255; return r; };

    ushort* S_Ob = (ushort*)alloc(ND * 2);
    ushort* S_Ib = (ushort*)alloc(ND * 2);
    ushort* xb   = (ushort*)alloc(ND * 2);
    ushort* rb   = (ushort*)alloc((size_t)R_REL * DIM * 2);
    uint2* erec  = (uint2*)alloc((size_t)N_EDGES * 8);
    ushort* Wb   = (ushort*)alloc((size_t)DIM * 384 * 2);
    float* bias0 = (float*)alloc(DIM * 4);
    float* bO3   = (float*)alloc(DIM * 4);
    float* bI3   = (float*)alloc(DIM * 4);
    float* colsum= (float*)alloc(DIM * 4);
    float* colsq = (float*)alloc(DIM * 4);
    float* cntO  = (float*)alloc(N_NODES * 4);
    float* cntI  = (float*)alloc(N_NODES * 4);
    int*   cnt   = (int*)alloc(N_NODES * 4);
    int*   offs  = (int*)alloc((N_NODES + 1) * 4);
    int*   chunksum  = (int*)alloc(NCHUNK * 4);
    int*   chunkbase = (int*)alloc(NCHUNK * 4);
    int*   flag  = (int*)alloc(4);

    float* y    = (float*)d_out;               // n_out region, N*D floats
    float* rout = (float*)d_out + ND;          // r_out region, R*D floats

    hipMemsetAsync(cnt, 0, N_NODES * sizeof(int), stream);
    hipMemsetAsync(colsum, 0, DIM * sizeof(float), stream);
    hipMemsetAsync(colsq, 0, DIM * sizeof(float), stream);

    detect_mask_kernel<<<1, 1, 0, stream>>>((const unsigned char*)in_mask,
                                            (const unsigned char*)out_mask, flag);
    tobf16_kernel<<<(int)((ND / 4 + 255) / 256), 256, 0, stream>>>(x, xb, (int)(ND / 4));
    tobf16_kernel<<<(R_REL * DIM / 4 + 255) / 256, 256, 0, stream>>>(r_feats, rb, R_REL * DIM / 4);
    prep_weights_kernel<<<128, 384, 0, stream>>>(W_O_w, W_I_w, W_S_w, Wb);
    prep_bias_kernel<<<1, 128, 0, stream>>>(W_S_w, W_S_b, W_O_b, W_I_b, loop_rel,
                                            bias0, bO3, bI3);
    rout_kernel<<<R_REL, 128, 0, stream>>>(r_feats, W_R_w, W_R_b, rout);

    // CSR build
    hist_kernel<<<(N_EDGES + 255) / 256, 256, 0, stream>>>(dst, cnt);
    scan1_kernel<<<NCHUNK, 256, 0, stream>>>(cnt, chunksum);
    scan2_kernel<<<1, 1, 0, stream>>>(chunksum, chunkbase, offs);
    scan3_kernel<<<NCHUNK, 256, 0, stream>>>(cnt, chunkbase, offs);
    fill_kernel<<<(N_EDGES + 255) / 256, 256, 0, stream>>>(
        dst, src, etype, norm, out_mask, flag, cnt, erec);

    aggregate_kernel<<<(N_NODES + 3) / 4, 256, 0, stream>>>(
        (const unsigned int*)xb, (const unsigned int*)rb, erec, offs,
        (unsigned int*)S_Ob, (unsigned int*)S_Ib, cntO, cntI);

    gemm_kernel<<<(N_NODES + 127) / 128, 256, 0, stream>>>(
        xb, S_Ob, S_Ib, Wb, bias0, bO3, bI3, cntO, cntI, y, colsum, colsq);

    bn_apply_kernel<<<2048, 256, 0, stream>>>(y, colsum, colsq, bn_gamma, bn_beta);
}